// Round 1
// baseline (326.976 us; speedup 1.0000x reference)
//
#include <hip/hip_runtime.h>
#include <hip/hip_bf16.h>

#define T_ 64
#define B_ 8
#define H_ 128
#define NH_ 4
#define D_ 256
#define TB_ 512          // T_*B_
#define EPS_ 1e-5f

__device__ __forceinline__ float silu_(float x){ return x / (1.0f + __expf(-x)); }
__device__ __forceinline__ float sigm_(float x){ return 1.0f / (1.0f + __expf(-x)); }

// ---------------- K1: batchnorm over batch (B=8) per (t, feature) ----------------
__global__ void k_bn1(const float* __restrict__ x, const float* __restrict__ g,
                      const float* __restrict__ bb, float* __restrict__ u){
  int id = blockIdx.x*256 + threadIdx.x;
  if (id >= T_*H_) return;
  int t = id >> 7, hf = id & 127;
  const float* xp = x + t*(B_*H_) + hf;
  float v0[B_]; float mu = 0.f;
  #pragma unroll
  for (int b=0;b<B_;b++){ v0[b] = xp[b*H_]; mu += v0[b]; }
  mu *= 0.125f;
  float var = 0.f;
  #pragma unroll
  for (int b=0;b<B_;b++){ float dd = v0[b]-mu; var += dd*dd; }
  var *= 0.125f;
  float sc = (1.0f/sqrtf(var + EPS_)) * g[hf];
  float bs = bb[hf];
  float* up = u + t*(B_*H_) + hf;
  #pragma unroll
  for (int b=0;b<B_;b++) up[b*H_] = (v0[b]-mu)*sc + bs;
}

// ---------------- K2: xin = u@Wup1+b1 ; trig = silu(u@Wup2+b2) ----------------
__global__ void k_up(const float* __restrict__ u, const float* __restrict__ W1,
                     const float* __restrict__ b1, const float* __restrict__ W2,
                     const float* __restrict__ b2, float* __restrict__ xin,
                     float* __restrict__ trig){
  __shared__ float us[H_];
  int row = blockIdx.x, e = threadIdx.x;
  if (e < H_) us[e] = u[row*H_ + e];
  __syncthreads();
  float a1 = 0.f, a2 = 0.f;
  #pragma unroll 4
  for (int hh=0; hh<H_; hh++){
    float uv = us[hh];
    a1 = fmaf(uv, W1[hh*D_ + e], a1);
    a2 = fmaf(uv, W2[hh*D_ + e], a2);
  }
  a1 += b1[e]; a2 += b2[e];
  xin[row*D_ + e] = a1;
  trig[row*D_ + e] = silu_(a2);
}

// ---------------- K3: depthwise conv (k=4, SAME: pad 1 left / 2 right) + silu ----------------
__global__ void k_conv(const float* __restrict__ xin, const float* __restrict__ ck,
                       const float* __restrict__ cb, float* __restrict__ qk){
  int id = blockIdx.x*256 + threadIdx.x;          // over T*NH*B*D
  int d = id & 255; int r = id >> 8;              // r = (t*NH+h)*B+b
  int b = r & 7; int hb2 = r >> 3; int h = hb2 & 3; int t = hb2 >> 2;
  const float* xr = xin + (t*B_ + b)*D_;
  float acc = cb[h];
  #pragma unroll
  for (int w = 0; w < 4; w++){
    int idx = d + w - 1;
    float xv = (idx >= 0 && idx < D_) ? xr[idx] : 0.0f;
    acc = fmaf(xv, ck[w*NH_ + h], acc);
  }
  qk[id] = silu_(acc);
}

// ---------------- K4: per-head 5 matmuls (q,k,v,outg,skip) ----------------
// block: one head (h = bx%4 -> XCD-local weights), 8 rows (t,b), 256 threads = output col e
__global__ __launch_bounds__(256) void k_heads(
    const float* __restrict__ qk, const float* __restrict__ xin,
    const float* __restrict__ Wq, const float* __restrict__ bq,
    const float* __restrict__ Wk, const float* __restrict__ bk,
    const float* __restrict__ Wv, const float* __restrict__ bv,
    const float* __restrict__ Wo, const float* __restrict__ bo,
    const float* __restrict__ Ws, const float* __restrict__ bsk,
    float* __restrict__ qo, float* __restrict__ ko, float* __restrict__ vo,
    float* __restrict__ og, float* __restrict__ hb){
  __shared__ __align__(16) float qks[8][D_];
  __shared__ __align__(16) float xis[8][D_];
  int h  = blockIdx.x & (NH_-1);
  int rg = blockIdx.x >> 2;
  int r0 = rg*8;
  int e = threadIdx.x;
  for (int i = e; i < 8*D_; i += 256){
    int rr = i >> 8, dd = i & 255;
    int row = r0 + rr;                 // t*B + b
    int t = row >> 3, b = row & 7;
    qks[rr][dd] = qk[(((t*NH_ + h)*B_ + b) << 8) + dd];
    xis[rr][dd] = xin[(row << 8) + dd];
  }
  __syncthreads();
  float aq[8]={0,0,0,0,0,0,0,0}, ak[8]={0,0,0,0,0,0,0,0}, av[8]={0,0,0,0,0,0,0,0};
  float ao[8]={0,0,0,0,0,0,0,0}, as2[8]={0,0,0,0,0,0,0,0};
  const float* pq = Wq + h*D_*D_ + e;
  const float* pk = Wk + h*D_*D_ + e;
  const float* pv = Wv + h*D_*D_ + e;
  const float* po = Wo + h*D_*D_ + e;
  const float* ps = Ws + h*D_*D_ + e;
  for (int d = 0; d < D_; d += 4){
    float qbuf[8][4], xbuf[8][4];
    #pragma unroll
    for (int r = 0; r < 8; r++){
      float4 a = *(const float4*)&qks[r][d];
      qbuf[r][0]=a.x; qbuf[r][1]=a.y; qbuf[r][2]=a.z; qbuf[r][3]=a.w;
      float4 c2 = *(const float4*)&xis[r][d];
      xbuf[r][0]=c2.x; xbuf[r][1]=c2.y; xbuf[r][2]=c2.z; xbuf[r][3]=c2.w;
    }
    #pragma unroll
    for (int k2 = 0; k2 < 4; k2++){
      float wq = pq[(d+k2)*D_], wk = pk[(d+k2)*D_], wv = pv[(d+k2)*D_];
      float wo = po[(d+k2)*D_], ws = ps[(d+k2)*D_];
      #pragma unroll
      for (int r = 0; r < 8; r++){
        aq[r]  = fmaf(qbuf[r][k2], wq, aq[r]);
        ak[r]  = fmaf(qbuf[r][k2], wk, ak[r]);
        as2[r] = fmaf(qbuf[r][k2], ws, as2[r]);
        av[r]  = fmaf(xbuf[r][k2], wv, av[r]);
        ao[r]  = fmaf(xbuf[r][k2], wo, ao[r]);
      }
    }
  }
  float vbq = bq[h*D_+e], vbk = bk[h*D_+e], vbv = bv[h*D_+e];
  float vbo = bo[h*D_+e], vbs = bsk[h*D_+e];
  #pragma unroll
  for (int r = 0; r < 8; r++){
    int row = r0 + r; int t = row >> 3, b = row & 7;
    int o = (((t*NH_ + h)*B_ + b) << 8) + e;
    qo[o] = aq[r] + vbq;
    ko[o] = (ak[r] + vbk) * 0.0625f;     // * 1/sqrt(D)
    vo[o] = av[r] + vbv;
    og[o] = sigm_(ao[r] + vbo);
    hb[o] = as2[r] + vbs;                // skip term, attention adds on top
  }
}

// ---------------- K5: it/ft gate dots ----------------
__global__ void k_gates(const float* __restrict__ xin, const float* __restrict__ Wi,
                        const float* __restrict__ bi, const float* __restrict__ Wf,
                        const float* __restrict__ bfv, float* __restrict__ itb,
                        float* __restrict__ ftb){
  int hb2 = blockIdx.x; int h = hb2 >> 3, b = hb2 & 7;
  int tg = threadIdx.x >> 2, l4 = threadIdx.x & 3;
  const float* xr = xin + (tg*B_ + b)*D_ + l4*64;
  const float* wi = Wi + h*D_ + l4*64;
  const float* wf = Wf + h*D_ + l4*64;
  float ai = 0.f, af = 0.f;
  #pragma unroll 8
  for (int j = 0; j < 64; j++){
    float xv = xr[j];
    ai = fmaf(xv, wi[j], ai);
    af = fmaf(xv, wf[j], af);
  }
  ai += __shfl_down(ai, 1); af += __shfl_down(af, 1);
  ai += __shfl_down(ai, 2); af += __shfl_down(af, 2);
  if (l4 == 0){
    itb[hb2*T_ + tg] = ai + bi[h];
    ftb[hb2*T_ + tg] = af + bfv[h];
  }
}

// ---------------- K6: closed-form gate scan ----------------
// m_t = F_t + max(0, G_t);  colterm_s = it_s - F_s;  rowbase_t = F_t - m_t = -max(0,G_t)
__global__ void k_scan(const float* __restrict__ itb, const float* __restrict__ ftb,
                       float* __restrict__ colterm, float* __restrict__ rowbase){
  int id = threadIdx.x;
  if (id >= NH_*B_) return;
  const float* itp = itb + id*T_;
  const float* ftp = ftb + id*T_;
  float F = 0.0f, G = -1e30f;
  for (int t = 0; t < T_; t++){
    F += ftp[t];
    float ct = itp[t] - F;
    G = fmaxf(G, ct);
    colterm[id*T_ + t] = ct;
    rowbase[id*T_ + t] = -fmaxf(0.0f, G);
  }
}

// ---------------- K7: masked decay attention per (h,b) ----------------
__global__ __launch_bounds__(256) void k_attn(
    const float* __restrict__ qo, const float* __restrict__ ko,
    const float* __restrict__ vo, const float* __restrict__ og,
    const float* __restrict__ colterm, const float* __restrict__ rowbase,
    float* __restrict__ hb){
  __shared__ float Qt[64*65];                 // transposed [dd][t], stride 65
  __shared__ float Kt[64*65];
  __shared__ __align__(16) float P2[64*68];   // [s][t], stride 68 (16B-aligned rows)
  __shared__ float scal[64];
  int hbx = blockIdx.x;                       // h*B + b
  int tid = threadIdx.x;
  int tg = tid >> 4, sg = tid & 15;           // 16x16 thread grid, 4x4 outputs each
  const float* Qg = qo + (hbx << 8);
  const float* Kg = ko + (hbx << 8);
  float acc[4][4] = {{0.f}};
  for (int c = 0; c < 4; c++){
    int d0 = c*64;
    for (int i = tid; i < 64*64; i += 256){
      int r = i >> 6, dd = i & 63;
      Qt[dd*65 + r] = Qg[r*8192 + d0 + dd];
      Kt[dd*65 + r] = Kg[r*8192 + d0 + dd];
    }
    __syncthreads();
    for (int dd = 0; dd < 64; dd++){
      float qv[4], kv[4];
      #pragma unroll
      for (int j = 0; j < 4; j++){
        qv[j] = Qt[dd*65 + tg*4 + j];
        kv[j] = Kt[dd*65 + sg*4 + j];
      }
      #pragma unroll
      for (int jt = 0; jt < 4; jt++)
        #pragma unroll
        for (int js = 0; js < 4; js++)
          acc[jt][js] = fmaf(qv[jt], kv[js], acc[jt][js]);
    }
    __syncthreads();
  }
  // mask + decay weights -> P2[s][t]
  const float* ct = colterm + hbx*T_;
  const float* rb = rowbase + hbx*T_;
  #pragma unroll
  for (int jt = 0; jt < 4; jt++){
    int t = tg*4 + jt;
    float rbt = rb[t];
    #pragma unroll
    for (int js = 0; js < 4; js++){
      int s = sg*4 + js;
      float p = (s <= t) ? __expf(ct[s] + rbt) * acc[jt][js] : 0.f;
      P2[s*68 + t] = p;
    }
  }
  __syncthreads();
  if (tid < 64){
    float sum = 0.f;
    for (int s = 0; s < 64; s++) sum += P2[s*68 + tid];
    scal[tid] = 1.0f / fmaxf(fabsf(sum), 1.0f);   // n.q rowsum -> scaler
  }
  __syncthreads();
  // phase 2: H_pre[t][e] = sum_s P[t][s] * V[s][e]; thread = column e
  float ac[64];
  #pragma unroll
  for (int t = 0; t < 64; t++) ac[t] = 0.f;
  const float* Vg = vo + (hbx << 8) + tid;
  for (int s = 0; s < 64; s++){
    float vv = Vg[s*8192];
    const float* pr = &P2[s*68];
    #pragma unroll
    for (int t4 = 0; t4 < 16; t4++){
      float4 pp = *(const float4*)(pr + t4*4);
      ac[t4*4+0] = fmaf(pp.x, vv, ac[t4*4+0]);
      ac[t4*4+1] = fmaf(pp.y, vv, ac[t4*4+1]);
      ac[t4*4+2] = fmaf(pp.z, vv, ac[t4*4+2]);
      ac[t4*4+3] = fmaf(pp.w, vv, ac[t4*4+3]);
    }
  }
  const float* Og = og + (hbx << 8) + tid;
  float* Hg = hb + (hbx << 8) + tid;
  #pragma unroll
  for (int t = 0; t < 64; t++){
    Hg[t*8192] += Og[t*8192] * ac[t] * scal[t];
  }
}

// ---------------- K8: batchnorm over (nh,b)=32 per (t,d) + reshape to [t][b][h*D+d] ----------------
__global__ void k_bn2(const float* __restrict__ hbuf, const float* __restrict__ g,
                      const float* __restrict__ bb, float* __restrict__ ho){
  int id = blockIdx.x*256 + threadIdx.x;        // T*D
  int t = id >> 8, d = id & 255;
  float v[32]; float mu = 0.f;
  const float* hp = hbuf + ((t*NH_*B_) << 8) + d;
  #pragma unroll
  for (int i = 0; i < 32; i++){ v[i] = hp[i*D_]; mu += v[i]; }
  mu *= (1.0f/32.0f);
  float var = 0.f;
  #pragma unroll
  for (int i = 0; i < 32; i++){ float dd = v[i]-mu; var += dd*dd; }
  var *= (1.0f/32.0f);
  float sc = (1.0f/sqrtf(var + EPS_)) * g[d];
  float bs = bb[d];
  float* hop = ho + t*(B_*NH_*D_);
  #pragma unroll
  for (int i = 0; i < 32; i++){                 // i = h*B + b
    int hh = i >> 3, b = i & 7;
    hop[b*(NH_*D_) + hh*D_ + d] = (v[i]-mu)*sc + bs;
  }
}

// ---------------- K9: z = (ho @ Wpoll + bpoll) * trig ----------------
__global__ __launch_bounds__(256) void k_poll(
    const float* __restrict__ ho, const float* __restrict__ Wp,
    const float* __restrict__ bp, const float* __restrict__ trig,
    float* __restrict__ z){
  __shared__ float hos[8][NH_*D_];              // 32 KB
  int r0 = blockIdx.x*8, e = threadIdx.x;
  for (int i = e; i < 8*NH_*D_; i += 256){
    int rr = i >> 10, j = i & 1023;
    hos[rr][j] = ho[(r0+rr)*(NH_*D_) + j];
  }
  __syncthreads();
  float acc[8] = {0,0,0,0,0,0,0,0};
  for (int j = 0; j < NH_*D_; j++){
    float w2 = Wp[j*D_ + e];
    #pragma unroll
    for (int r = 0; r < 8; r++) acc[r] = fmaf(hos[r][j], w2, acc[r]);
  }
  float bpe = bp[e];
  #pragma unroll
  for (int r = 0; r < 8; r++){
    int row = r0 + r;
    z[row*D_ + e] = (acc[r] + bpe) * trig[row*D_ + e];
  }
}

// ---------------- K10: y = z @ Wdown + bdown + x ----------------
__global__ void k_down(const float* __restrict__ z, const float* __restrict__ Wd,
                       const float* __restrict__ bd, const float* __restrict__ x,
                       float* __restrict__ y){
  __shared__ float zs[2][D_];
  int r0 = blockIdx.x*2;
  int tid = threadIdx.x;
  for (int i = tid; i < 2*D_; i += 256){ zs[i >> 8][i & 255] = z[r0*D_ + i]; }
  __syncthreads();
  int r = tid >> 7, hh = tid & 127;
  float acc = 0.f;
  #pragma unroll 4
  for (int e = 0; e < D_; e++) acc = fmaf(zs[r][e], Wd[e*H_ + hh], acc);
  int row = r0 + r;
  y[row*H_ + hh] = acc + bd[hh] + x[row*H_ + hh];
}

extern "C" void kernel_launch(void* const* d_in, const int* in_sizes, int n_in,
                              void* d_out, int out_size, void* d_ws, size_t ws_size,
                              hipStream_t stream){
  const float* x     = (const float*)d_in[0];
  const float* Wq    = (const float*)d_in[1];
  const float* bq    = (const float*)d_in[2];
  const float* Wk    = (const float*)d_in[3];
  const float* bk    = (const float*)d_in[4];
  const float* Wv    = (const float*)d_in[5];
  const float* bv    = (const float*)d_in[6];
  const float* ck    = (const float*)d_in[7];
  const float* cb    = (const float*)d_in[8];
  const float* Wi    = (const float*)d_in[9];
  const float* bi    = (const float*)d_in[10];
  const float* Wf    = (const float*)d_in[11];
  const float* bf    = (const float*)d_in[12];
  const float* Wo    = (const float*)d_in[13];
  const float* bo    = (const float*)d_in[14];
  const float* Wsk   = (const float*)d_in[15];
  const float* bsk   = (const float*)d_in[16];
  const float* bn1s  = (const float*)d_in[17];
  const float* bn1b  = (const float*)d_in[18];
  const float* bn2s  = (const float*)d_in[19];
  const float* bn2b  = (const float*)d_in[20];
  const float* Wup1  = (const float*)d_in[21];
  const float* bup1  = (const float*)d_in[22];
  const float* Wup2  = (const float*)d_in[23];
  const float* bup2  = (const float*)d_in[24];
  const float* Wp    = (const float*)d_in[25];
  const float* bp    = (const float*)d_in[26];
  const float* Wd    = (const float*)d_in[27];
  const float* bd    = (const float*)d_in[28];
  float* y = (float*)d_out;

  float* w = (float*)d_ws;
  float* u    = w;  w += T_*B_*H_;
  float* xin  = w;  w += T_*B_*D_;
  float* trig = w;  w += T_*B_*D_;
  float* qk   = w;  w += T_*NH_*B_*D_;
  float* qo   = w;  w += T_*NH_*B_*D_;
  float* ko   = w;  w += T_*NH_*B_*D_;
  float* vo   = w;  w += T_*NH_*B_*D_;
  float* og   = w;  w += T_*NH_*B_*D_;
  float* hbuf = w;  w += T_*NH_*B_*D_;
  float* itb  = w;  w += NH_*B_*T_;
  float* ftb  = w;  w += NH_*B_*T_;
  float* ctm  = w;  w += NH_*B_*T_;
  float* rbs  = w;  w += NH_*B_*T_;
  float* ho   = w;  w += T_*B_*NH_*D_;
  float* z    = w;  w += T_*B_*D_;

  k_bn1  <<<(T_*H_+255)/256, 256, 0, stream>>>(x, bn1s, bn1b, u);
  k_up   <<<TB_, 256, 0, stream>>>(u, Wup1, bup1, Wup2, bup2, xin, trig);
  k_conv <<<(T_*NH_*B_*D_)/256, 256, 0, stream>>>(xin, ck, cb, qk);
  k_heads<<<NH_*64, 256, 0, stream>>>(qk, xin, Wq, bq, Wk, bk, Wv, bv, Wo, bo, Wsk, bsk,
                                      qo, ko, vo, og, hbuf);
  k_gates<<<NH_*B_, 256, 0, stream>>>(xin, Wi, bi, Wf, bf, itb, ftb);
  k_scan <<<1, 64, 0, stream>>>(itb, ftb, ctm, rbs);
  k_attn <<<NH_*B_, 256, 0, stream>>>(qo, ko, vo, og, ctm, rbs, hbuf);
  k_bn2  <<<(T_*D_)/256, 256, 0, stream>>>(hbuf, bn2s, bn2b, ho);
  k_poll <<<TB_/8, 256, 0, stream>>>(ho, Wp, bp, trig, z);
  k_down <<<TB_/2, 256, 0, stream>>>(z, Wd, bd, x, y);
}

// Round 2
// 242.245 us; speedup vs baseline: 1.3498x; 1.3498x over previous
//
#include <hip/hip_runtime.h>
#include <hip/hip_bf16.h>

#define T_ 64
#define B_ 8
#define H_ 128
#define NH_ 4
#define D_ 256
#define TB_ 512          // T_*B_
#define EPS_ 1e-5f

__device__ __forceinline__ float silu_(float x){ return x / (1.0f + __expf(-x)); }
__device__ __forceinline__ float sigm_(float x){ return 1.0f / (1.0f + __expf(-x)); }

// ---------------- K1 fused: bn1 + up-proj (Wup1/Wup2) + conv + gate dots ----------------
// grid = T_ * 2 (t, b-half), block = 256. Each block handles 4 batch rows of one t.
__global__ __launch_bounds__(256) void k_front(
    const float* __restrict__ x, const float* __restrict__ bn1s, const float* __restrict__ bn1b,
    const float* __restrict__ W1, const float* __restrict__ b1,
    const float* __restrict__ W2, const float* __restrict__ b2,
    const float* __restrict__ ck, const float* __restrict__ cb,
    const float* __restrict__ Wi, const float* __restrict__ bi,
    const float* __restrict__ Wf, const float* __restrict__ bfv,
    float* __restrict__ xin, float* __restrict__ trig, float* __restrict__ qk,
    float* __restrict__ itb, float* __restrict__ ftb){
  __shared__ __align__(16) float us[H_][4];    // u[hh][b-local]
  __shared__ __align__(16) float xs[4][D_];    // xin rows (b-local)
  int t = blockIdx.x >> 1;
  int bh = blockIdx.x & 1;                     // b-half: rows bh*4 .. bh*4+3
  int tid = threadIdx.x;
  // ---- bn1: thread hf < 128 computes stats over all 8 b, keeps our 4 ----
  if (tid < H_){
    int hf = tid;
    const float* xp = x + t*(B_*H_) + hf;
    float v0[8]; float mu = 0.f;
    #pragma unroll
    for (int b = 0; b < 8; b++){ v0[b] = xp[b*H_]; mu += v0[b]; }
    mu *= 0.125f;
    float var = 0.f;
    #pragma unroll
    for (int b = 0; b < 8; b++){ float dd = v0[b]-mu; var += dd*dd; }
    var *= 0.125f;
    float sc = (1.0f/sqrtf(var + EPS_)) * bn1s[hf];
    float bs = bn1b[hf];
    #pragma unroll
    for (int bl = 0; bl < 4; bl++) us[hf][bl] = (v0[bh*4+bl]-mu)*sc + bs;
  }
  __syncthreads();
  // ---- up-proj: thread e computes col e for 4 rows, both matrices ----
  int e = tid;
  float a1[4] = {0,0,0,0}, a2[4] = {0,0,0,0};
  for (int hh = 0; hh < H_; hh++){
    float w1 = W1[hh*D_ + e];
    float w2 = W2[hh*D_ + e];
    float4 uv = *(const float4*)&us[hh][0];
    a1[0] = fmaf(uv.x, w1, a1[0]); a2[0] = fmaf(uv.x, w2, a2[0]);
    a1[1] = fmaf(uv.y, w1, a1[1]); a2[1] = fmaf(uv.y, w2, a2[1]);
    a1[2] = fmaf(uv.z, w1, a1[2]); a2[2] = fmaf(uv.z, w2, a2[2]);
    a1[3] = fmaf(uv.w, w1, a1[3]); a2[3] = fmaf(uv.w, w2, a2[3]);
  }
  float be1 = b1[e], be2 = b2[e];
  #pragma unroll
  for (int bl = 0; bl < 4; bl++){
    int row = t*B_ + bh*4 + bl;
    float v1 = a1[bl] + be1;
    xs[bl][e] = v1;
    xin[row*D_ + e] = v1;
    trig[row*D_ + e] = silu_(a2[bl] + be2);
  }
  __syncthreads();
  // ---- depthwise conv k=4 (pad 1 left, 2 right) + silu ----
  {
    int d = e;
    #pragma unroll
    for (int h = 0; h < NH_; h++){
      float c0 = ck[0*NH_+h], c1 = ck[1*NH_+h], c2 = ck[2*NH_+h], c3 = ck[3*NH_+h];
      float cbh = cb[h];
      #pragma unroll
      for (int bl = 0; bl < 4; bl++){
        float xm1 = (d >= 1)   ? xs[bl][d-1] : 0.f;
        float x0  =              xs[bl][d];
        float xp1 = (d <= 254) ? xs[bl][d+1] : 0.f;
        float xp2 = (d <= 253) ? xs[bl][d+2] : 0.f;
        float acc = cbh;
        acc = fmaf(xm1, c0, acc); acc = fmaf(x0, c1, acc);
        acc = fmaf(xp1, c2, acc); acc = fmaf(xp2, c3, acc);
        int b = bh*4 + bl;
        qk[(((t*NH_ + h)*B_ + b) << 8) + d] = silu_(acc);
      }
    }
  }
  // ---- gate dots: 16 dots (4h x 4b-local), 16 lanes each ----
  {
    int dt = tid >> 4, ln = tid & 15;          // dot index, lane in dot
    int h = dt >> 2, bl = dt & 3;
    int b = bh*4 + bl;
    float ai = 0.f, af = 0.f;
    const float* wi = Wi + h*D_;
    const float* wf = Wf + h*D_;
    #pragma unroll
    for (int jj = 0; jj < 16; jj++){
      int j = ln + 16*jj;
      float xv = xs[bl][j];
      ai = fmaf(xv, wi[j], ai);
      af = fmaf(xv, wf[j], af);
    }
    ai += __shfl_down(ai, 1); af += __shfl_down(af, 1);
    ai += __shfl_down(ai, 2); af += __shfl_down(af, 2);
    ai += __shfl_down(ai, 4); af += __shfl_down(af, 4);
    ai += __shfl_down(ai, 8); af += __shfl_down(af, 8);
    if (ln == 0){
      itb[(h*B_ + b)*T_ + t] = ai + bi[h];
      ftb[(h*B_ + b)*T_ + t] = af + bfv[h];
    }
  }
}

// ---------------- K4: per-head 5 matmuls (q,k,v,outg,skip) ----------------
__global__ __launch_bounds__(256) void k_heads(
    const float* __restrict__ qk, const float* __restrict__ xin,
    const float* __restrict__ Wq, const float* __restrict__ bq,
    const float* __restrict__ Wk, const float* __restrict__ bk,
    const float* __restrict__ Wv, const float* __restrict__ bv,
    const float* __restrict__ Wo, const float* __restrict__ bo,
    const float* __restrict__ Ws, const float* __restrict__ bsk,
    float* __restrict__ qo, float* __restrict__ ko, float* __restrict__ vo,
    float* __restrict__ og, float* __restrict__ hb){
  __shared__ __align__(16) float qks[8][D_];
  __shared__ __align__(16) float xis[8][D_];
  int h  = blockIdx.x & (NH_-1);
  int rg = blockIdx.x >> 2;
  int r0 = rg*8;
  int e = threadIdx.x;
  for (int i = e; i < 8*D_; i += 256){
    int rr = i >> 8, dd = i & 255;
    int row = r0 + rr;                 // t*B + b
    int t = row >> 3, b = row & 7;
    qks[rr][dd] = qk[(((t*NH_ + h)*B_ + b) << 8) + dd];
    xis[rr][dd] = xin[(row << 8) + dd];
  }
  __syncthreads();
  float aq[8]={0,0,0,0,0,0,0,0}, ak[8]={0,0,0,0,0,0,0,0}, av[8]={0,0,0,0,0,0,0,0};
  float ao[8]={0,0,0,0,0,0,0,0}, as2[8]={0,0,0,0,0,0,0,0};
  const float* pq = Wq + h*D_*D_ + e;
  const float* pk = Wk + h*D_*D_ + e;
  const float* pv = Wv + h*D_*D_ + e;
  const float* po = Wo + h*D_*D_ + e;
  const float* ps = Ws + h*D_*D_ + e;
  for (int d = 0; d < D_; d += 4){
    float qbuf[8][4], xbuf[8][4];
    #pragma unroll
    for (int r = 0; r < 8; r++){
      float4 a = *(const float4*)&qks[r][d];
      qbuf[r][0]=a.x; qbuf[r][1]=a.y; qbuf[r][2]=a.z; qbuf[r][3]=a.w;
      float4 c2 = *(const float4*)&xis[r][d];
      xbuf[r][0]=c2.x; xbuf[r][1]=c2.y; xbuf[r][2]=c2.z; xbuf[r][3]=c2.w;
    }
    #pragma unroll
    for (int k2 = 0; k2 < 4; k2++){
      float wq = pq[(d+k2)*D_], wk = pk[(d+k2)*D_], wv = pv[(d+k2)*D_];
      float wo = po[(d+k2)*D_], ws = ps[(d+k2)*D_];
      #pragma unroll
      for (int r = 0; r < 8; r++){
        aq[r]  = fmaf(qbuf[r][k2], wq, aq[r]);
        ak[r]  = fmaf(qbuf[r][k2], wk, ak[r]);
        as2[r] = fmaf(qbuf[r][k2], ws, as2[r]);
        av[r]  = fmaf(xbuf[r][k2], wv, av[r]);
        ao[r]  = fmaf(xbuf[r][k2], wo, ao[r]);
      }
    }
  }
  float vbq = bq[h*D_+e], vbk = bk[h*D_+e], vbv = bv[h*D_+e];
  float vbo = bo[h*D_+e], vbs = bsk[h*D_+e];
  #pragma unroll
  for (int r = 0; r < 8; r++){
    int row = r0 + r; int t = row >> 3, b = row & 7;
    int o = (((t*NH_ + h)*B_ + b) << 8) + e;
    qo[o] = aq[r] + vbq;
    ko[o] = (ak[r] + vbk) * 0.0625f;     // * 1/sqrt(D)
    vo[o] = av[r] + vbv;
    og[o] = sigm_(ao[r] + vbo);
    hb[o] = as2[r] + vbs;                // skip term, attention adds on top
  }
}

// ---------------- K6: closed-form gate scan via wave prefix ops ----------------
// m_t = F_t + max(0, G_t);  colterm_s = it_s - F_s;  rowbase_t = -max(0,G_t)
__global__ void k_scan(const float* __restrict__ itb, const float* __restrict__ ftb,
                       float* __restrict__ colterm, float* __restrict__ rowbase){
  int id = blockIdx.x;                  // h*B + b  (32 blocks)
  int t = threadIdx.x;                  // 64 lanes = timesteps
  float ft = ftb[id*T_ + t];
  float it = itb[id*T_ + t];
  float F = ft;
  #pragma unroll
  for (int off = 1; off < 64; off <<= 1){
    float v2 = __shfl_up(F, off);
    if (t >= off) F += v2;
  }
  float ct = it - F;
  float G = ct;
  #pragma unroll
  for (int off = 1; off < 64; off <<= 1){
    float v2 = __shfl_up(G, off);
    if (t >= off) G = fmaxf(G, v2);
  }
  colterm[id*T_ + t] = ct;
  rowbase[id*T_ + t] = -fmaxf(0.f, G);
}

// ---------------- K7: masked decay attention, t-quarter per block ----------------
#define TQ_ 16
__global__ __launch_bounds__(256) void k_attn(
    const float* __restrict__ qo, const float* __restrict__ ko,
    const float* __restrict__ vo, const float* __restrict__ og,
    const float* __restrict__ colterm, const float* __restrict__ rowbase,
    float* __restrict__ hb){
  __shared__ float Qc[64*17];                  // [dd][tl] stride 17
  __shared__ float Kc[64*65];                  // [dd][s]  stride 65
  __shared__ __align__(16) float P2[64][20];   // [s][tl]  stride 20 (80B rows)
  __shared__ float scal[TQ_];
  int hbx = blockIdx.x >> 2;                   // h*B + b
  int tqi = blockIdx.x & 3;
  int t0  = tqi*TQ_;
  int tid = threadIdx.x;
  int hb_off = hbx << 8;
  const float* Qg = qo + hb_off;
  const float* Kg = ko + hb_off;
  int tg = tid >> 5, sg = tid & 31;            // t rows tg*2+{0,1}, s cols sg*2+{0,1}
  float acc[2][2] = {{0.f,0.f},{0.f,0.f}};
  for (int c = 0; c < 4; c++){
    int d0 = c*64;
    for (int i = tid; i < TQ_*64; i += 256){
      int r = i >> 6, dd = i & 63;
      Qc[dd*17 + r] = Qg[(t0+r)*8192 + d0 + dd];
    }
    for (int i = tid; i < 64*64; i += 256){
      int s = i >> 6, dd = i & 63;
      Kc[dd*65 + s] = Kg[s*8192 + d0 + dd];
    }
    __syncthreads();
    for (int dd = 0; dd < 64; dd++){
      float q0 = Qc[dd*17 + tg*2], q1 = Qc[dd*17 + tg*2 + 1];
      float k0 = Kc[dd*65 + sg*2], k1 = Kc[dd*65 + sg*2 + 1];
      acc[0][0] = fmaf(q0, k0, acc[0][0]);
      acc[0][1] = fmaf(q0, k1, acc[0][1]);
      acc[1][0] = fmaf(q1, k0, acc[1][0]);
      acc[1][1] = fmaf(q1, k1, acc[1][1]);
    }
    __syncthreads();
  }
  const float* ct = colterm + hbx*T_;
  const float* rb = rowbase + hbx*T_;
  #pragma unroll
  for (int jt = 0; jt < 2; jt++){
    int tl = tg*2 + jt; int tglob = t0 + tl;
    float rbt = rb[tglob];
    #pragma unroll
    for (int js = 0; js < 2; js++){
      int s = sg*2 + js;
      float p = (s <= tglob) ? __expf(ct[s] + rbt) * acc[jt][js] : 0.f;
      P2[s][tl] = p;
    }
  }
  __syncthreads();
  if (tid < TQ_){
    float sum = 0.f;
    for (int s = 0; s < 64; s++) sum += P2[s][tid];
    scal[tid] = 1.0f / fmaxf(fabsf(sum), 1.0f);     // 1/max(|n.q|,1)
  }
  __syncthreads();
  float ac[TQ_];
  #pragma unroll
  for (int i = 0; i < TQ_; i++) ac[i] = 0.f;
  const float* Vg = vo + hb_off + tid;
  for (int s = 0; s < 64; s++){
    float vv = Vg[s*8192];
    const float* pr = &P2[s][0];
    #pragma unroll
    for (int t4 = 0; t4 < 4; t4++){
      float4 pp = *(const float4*)(pr + t4*4);
      ac[t4*4+0] = fmaf(pp.x, vv, ac[t4*4+0]);
      ac[t4*4+1] = fmaf(pp.y, vv, ac[t4*4+1]);
      ac[t4*4+2] = fmaf(pp.z, vv, ac[t4*4+2]);
      ac[t4*4+3] = fmaf(pp.w, vv, ac[t4*4+3]);
    }
  }
  const float* Og = og + hb_off + tid;
  float* Hg = hb + hb_off + tid;
  #pragma unroll
  for (int tl = 0; tl < TQ_; tl++){
    int tglob = t0 + tl;
    Hg[tglob*8192] += Og[tglob*8192] * ac[tl] * scal[tl];
  }
}

// ---------------- K8: batchnorm over (nh,b)=32 per (t,d) + reshape ----------------
__global__ void k_bn2(const float* __restrict__ hbuf, const float* __restrict__ g,
                      const float* __restrict__ bb, float* __restrict__ ho){
  int id = blockIdx.x*256 + threadIdx.x;        // T*D
  int t = id >> 8, d = id & 255;
  float v[32]; float mu = 0.f;
  const float* hp = hbuf + ((t*NH_*B_) << 8) + d;
  #pragma unroll
  for (int i = 0; i < 32; i++){ v[i] = hp[i*D_]; mu += v[i]; }
  mu *= (1.0f/32.0f);
  float var = 0.f;
  #pragma unroll
  for (int i = 0; i < 32; i++){ float dd = v[i]-mu; var += dd*dd; }
  var *= (1.0f/32.0f);
  float sc = (1.0f/sqrtf(var + EPS_)) * g[d];
  float bs = bb[d];
  float* hop = ho + t*(B_*NH_*D_);
  #pragma unroll
  for (int i = 0; i < 32; i++){                 // i = h*B + b
    int hh = i >> 3, b = i & 7;
    hop[b*(NH_*D_) + hh*D_ + d] = (v[i]-mu)*sc + bs;
  }
}

// ---------------- K9: z = (ho @ Wpoll + bpoll) * trig — high-occupancy retile ----------------
// grid = 128 rowgroups x 4 colgroups; block 256 = 4 rows x 64 cols
__global__ __launch_bounds__(256) void k_poll(
    const float* __restrict__ ho, const float* __restrict__ Wp,
    const float* __restrict__ bp, const float* __restrict__ trig,
    float* __restrict__ z){
  __shared__ __align__(16) float hos[4][NH_*D_];    // 16 KB
  int rg = blockIdx.x >> 2;
  int cg = blockIdx.x & 3;
  int r0 = rg*4;
  int tid = threadIdx.x;
  #pragma unroll
  for (int r = 0; r < 4; r++){
    float4 v4 = *(const float4*)&ho[(r0+r)*(NH_*D_) + tid*4];
    *(float4*)&hos[r][tid*4] = v4;
  }
  __syncthreads();
  int tr = tid >> 6;
  int e  = (tid & 63) + cg*64;
  const float* wp = Wp + e;
  float acc = 0.f;
  for (int j = 0; j < NH_*D_; j += 4){
    float4 h4 = *(const float4*)&hos[tr][j];
    acc = fmaf(h4.x, wp[(j+0)*D_], acc);
    acc = fmaf(h4.y, wp[(j+1)*D_], acc);
    acc = fmaf(h4.z, wp[(j+2)*D_], acc);
    acc = fmaf(h4.w, wp[(j+3)*D_], acc);
  }
  int row = r0 + tr;
  z[row*D_ + e] = (acc + bp[e]) * trig[row*D_ + e];
}

// ---------------- K10: y = z @ Wdown + bdown + x ----------------
__global__ void k_down(const float* __restrict__ z, const float* __restrict__ Wd,
                       const float* __restrict__ bd, const float* __restrict__ x,
                       float* __restrict__ y){
  __shared__ float zs[2][D_];
  int r0 = blockIdx.x*2;
  int tid = threadIdx.x;
  for (int i = tid; i < 2*D_; i += 256){ zs[i >> 8][i & 255] = z[r0*D_ + i]; }
  __syncthreads();
  int r = tid >> 7, hh = tid & 127;
  float acc = 0.f;
  #pragma unroll 4
  for (int e = 0; e < D_; e++) acc = fmaf(zs[r][e], Wd[e*H_ + hh], acc);
  int row = r0 + r;
  y[row*H_ + hh] = acc + bd[hh] + x[row*H_ + hh];
}

extern "C" void kernel_launch(void* const* d_in, const int* in_sizes, int n_in,
                              void* d_out, int out_size, void* d_ws, size_t ws_size,
                              hipStream_t stream){
  const float* x     = (const float*)d_in[0];
  const float* Wq    = (const float*)d_in[1];
  const float* bq    = (const float*)d_in[2];
  const float* Wk    = (const float*)d_in[3];
  const float* bk    = (const float*)d_in[4];
  const float* Wv    = (const float*)d_in[5];
  const float* bv    = (const float*)d_in[6];
  const float* ck    = (const float*)d_in[7];
  const float* cb    = (const float*)d_in[8];
  const float* Wi    = (const float*)d_in[9];
  const float* bi    = (const float*)d_in[10];
  const float* Wf    = (const float*)d_in[11];
  const float* bf    = (const float*)d_in[12];
  const float* Wo    = (const float*)d_in[13];
  const float* bo    = (const float*)d_in[14];
  const float* Wsk   = (const float*)d_in[15];
  const float* bsk   = (const float*)d_in[16];
  const float* bn1s  = (const float*)d_in[17];
  const float* bn1b  = (const float*)d_in[18];
  const float* bn2s  = (const float*)d_in[19];
  const float* bn2b  = (const float*)d_in[20];
  const float* Wup1  = (const float*)d_in[21];
  const float* bup1  = (const float*)d_in[22];
  const float* Wup2  = (const float*)d_in[23];
  const float* bup2  = (const float*)d_in[24];
  const float* Wp    = (const float*)d_in[25];
  const float* bp    = (const float*)d_in[26];
  const float* Wd    = (const float*)d_in[27];
  const float* bd    = (const float*)d_in[28];
  float* y = (float*)d_out;

  float* w = (float*)d_ws;
  float* u    = w;  w += T_*B_*H_;    // unused (fused) — kept for layout stability
  float* xin  = w;  w += T_*B_*D_;
  float* trig = w;  w += T_*B_*D_;
  float* qk   = w;  w += T_*NH_*B_*D_;
  float* qo   = w;  w += T_*NH_*B_*D_;
  float* ko   = w;  w += T_*NH_*B_*D_;
  float* vo   = w;  w += T_*NH_*B_*D_;
  float* og   = w;  w += T_*NH_*B_*D_;
  float* hbuf = w;  w += T_*NH_*B_*D_;
  float* itb  = w;  w += NH_*B_*T_;
  float* ftb  = w;  w += NH_*B_*T_;
  float* ctm  = w;  w += NH_*B_*T_;
  float* rbs  = w;  w += NH_*B_*T_;
  float* ho   = w;  w += T_*B_*NH_*D_;
  float* z    = w;  w += T_*B_*D_;
  (void)u;

  k_front<<<T_*2, 256, 0, stream>>>(x, bn1s, bn1b, Wup1, bup1, Wup2, bup2,
                                    ck, cb, Wi, bi, Wf, bf, xin, trig, qk, itb, ftb);
  k_heads<<<NH_*64, 256, 0, stream>>>(qk, xin, Wq, bq, Wk, bk, Wv, bv, Wo, bo, Wsk, bsk,
                                      qo, ko, vo, og, hbuf);
  k_scan <<<NH_*B_, 64, 0, stream>>>(itb, ftb, ctm, rbs);
  k_attn <<<NH_*B_*4, 256, 0, stream>>>(qo, ko, vo, og, ctm, rbs, hbuf);
  k_bn2  <<<(T_*D_)/256, 256, 0, stream>>>(hbuf, bn2s, bn2b, ho);
  k_poll <<<128*4, 256, 0, stream>>>(ho, Wp, bp, trig, z);
  k_down <<<TB_/2, 256, 0, stream>>>(z, Wd, bd, x, y);
}

// Round 3
// 207.765 us; speedup vs baseline: 1.5738x; 1.1660x over previous
//
#include <hip/hip_runtime.h>
#include <hip/hip_bf16.h>

#define T_ 64
#define B_ 8
#define H_ 128
#define NH_ 4
#define D_ 256
#define TB_ 512          // T_*B_
#define EPS_ 1e-5f

typedef short bf16x8 __attribute__((ext_vector_type(8)));
typedef float f32x4 __attribute__((ext_vector_type(4)));

__device__ __forceinline__ float silu_(float x){ return x / (1.0f + __expf(-x)); }
__device__ __forceinline__ float sigm_(float x){ return 1.0f / (1.0f + __expf(-x)); }
__device__ __forceinline__ unsigned short tobf_(float f){
  unsigned u = __float_as_uint(f);
  u += 0x7FFF + ((u >> 16) & 1);          // round-to-nearest-even
  return (unsigned short)(u >> 16);
}

// ---------------- K0: convert+transpose 5 weight tensors to bf16 [h][n][k] ----------------
// grid = 5 mats x 4 heads x 16 (64x64 tiles); block 256
__global__ __launch_bounds__(256) void k_cvtw(
    const float* __restrict__ Wq, const float* __restrict__ Wk, const float* __restrict__ Ws,
    const float* __restrict__ Wv, const float* __restrict__ Wo,
    unsigned short* __restrict__ Wqt, unsigned short* __restrict__ Wkt,
    unsigned short* __restrict__ Wst, unsigned short* __restrict__ Wvt,
    unsigned short* __restrict__ Wot){
  __shared__ float tlf[64][65];
  int bid = blockIdx.x;
  int tile = bid & 15;
  int h    = (bid >> 4) & 3;
  int mat  = bid >> 6;
  int k0 = (tile >> 2) * 64, n0 = (tile & 3) * 64;
  const float* Win; unsigned short* Wout;
  switch (mat){
    case 0: Win = Wq; Wout = Wqt; break;
    case 1: Win = Wk; Wout = Wkt; break;
    case 2: Win = Ws; Wout = Wst; break;
    case 3: Win = Wv; Wout = Wvt; break;
    default: Win = Wo; Wout = Wot; break;
  }
  Win  += h * (D_*D_);
  Wout += h * (D_*D_);
  int tid = threadIdx.x;
  #pragma unroll
  for (int i = 0; i < 16; i++){
    int idx = tid + i*256;
    int kk = idx >> 6, nn = idx & 63;
    tlf[nn][kk] = Win[(k0+kk)*D_ + n0 + nn];
  }
  __syncthreads();
  int nn = tid >> 2;
  int kk0 = (tid & 3) * 16;
  bf16x8 v0, v1;
  #pragma unroll
  for (int i = 0; i < 8; i++){
    v0[i] = (short)tobf_(tlf[nn][kk0 + i]);
    v1[i] = (short)tobf_(tlf[nn][kk0 + 8 + i]);
  }
  unsigned short* op = Wout + (n0 + nn)*D_ + k0 + kk0;
  *(bf16x8*)(op)     = v0;
  *(bf16x8*)(op + 8) = v1;
}

// ---------------- K1: bn1 + up-proj; grid = T x 4 e-quarters, 8 rows/block ----------------
__global__ __launch_bounds__(256) void k_front(
    const float* __restrict__ x, const float* __restrict__ bn1s, const float* __restrict__ bn1b,
    const float* __restrict__ W1, const float* __restrict__ b1,
    const float* __restrict__ W2, const float* __restrict__ b2,
    float* __restrict__ xin, unsigned short* __restrict__ xinb, float* __restrict__ trig){
  __shared__ float us[H_][8];
  int t = blockIdx.x >> 2, eq = blockIdx.x & 3;
  int tid = threadIdx.x;
  if (tid < H_){
    const float* xp = x + t*(B_*H_) + tid;
    float v0[8]; float mu = 0.f;
    #pragma unroll
    for (int b = 0; b < 8; b++){ v0[b] = xp[b*H_]; mu += v0[b]; }
    mu *= 0.125f;
    float var = 0.f;
    #pragma unroll
    for (int b = 0; b < 8; b++){ float dd = v0[b]-mu; var += dd*dd; }
    var *= 0.125f;
    float sc = (1.0f/sqrtf(var + EPS_)) * bn1s[tid];
    float bs = bn1b[tid];
    #pragma unroll
    for (int b = 0; b < 8; b++) us[tid][b] = (v0[b]-mu)*sc + bs;
  }
  __syncthreads();
  int e_l = tid & 63, rg = tid >> 6;        // rg = wave id; rows rg*2, rg*2+1
  int e = eq*64 + e_l;
  float a10 = 0.f, a11 = 0.f, a20 = 0.f, a21 = 0.f;
  const float* w1p = W1 + e;
  const float* w2p = W2 + e;
  #pragma unroll 4
  for (int hh = 0; hh < H_; hh++){
    float w1v = w1p[hh*D_], w2v = w2p[hh*D_];
    float u0 = us[hh][rg*2], u1 = us[hh][rg*2+1];
    a10 = fmaf(u0, w1v, a10); a11 = fmaf(u1, w1v, a11);
    a20 = fmaf(u0, w2v, a20); a21 = fmaf(u1, w2v, a21);
  }
  float be1 = b1[e], be2 = b2[e];
  int row0 = t*B_ + rg*2;
  float vA = a10 + be1, vB = a11 + be1;
  xin[row0*D_ + e] = vA;        xin[(row0+1)*D_ + e] = vB;
  xinb[row0*D_ + e] = tobf_(vA); xinb[(row0+1)*D_ + e] = tobf_(vB);
  trig[row0*D_ + e] = silu_(a20 + be2);
  trig[(row0+1)*D_ + e] = silu_(a21 + be2);
}

// ---------------- K2: depthwise conv + silu (-> qkb bf16, head-major) + gate dots ----------------
__global__ __launch_bounds__(256) void k_cg(
    const float* __restrict__ xin, const float* __restrict__ ck, const float* __restrict__ cb,
    const float* __restrict__ Wi, const float* __restrict__ bi,
    const float* __restrict__ Wf, const float* __restrict__ bfv,
    unsigned short* __restrict__ qkb, float* __restrict__ itb, float* __restrict__ ftb){
  __shared__ float xs[D_];
  __shared__ float red[4][8];
  int row = blockIdx.x;                 // t*B + b
  int t = row >> 3, b = row & 7;
  int d = threadIdx.x;
  float xv = xin[row*D_ + d];
  xs[d] = xv;
  __syncthreads();
  float xm1 = (d >= 1)   ? xs[d-1] : 0.f;
  float xp1 = (d <= 254) ? xs[d+1] : 0.f;
  float xp2 = (d <= 253) ? xs[d+2] : 0.f;
  #pragma unroll
  for (int h = 0; h < NH_; h++){
    float acc = cb[h];
    acc = fmaf(xm1, ck[0*NH_+h], acc);
    acc = fmaf(xv,  ck[1*NH_+h], acc);
    acc = fmaf(xp1, ck[2*NH_+h], acc);
    acc = fmaf(xp2, ck[3*NH_+h], acc);
    qkb[(h*TB_ + row)*D_ + d] = tobf_(silu_(acc));
  }
  float p[8];
  #pragma unroll
  for (int h = 0; h < NH_; h++){
    p[h]   = xv * Wi[h*D_ + d];
    p[4+h] = xv * Wf[h*D_ + d];
  }
  #pragma unroll
  for (int off = 32; off >= 1; off >>= 1){
    #pragma unroll
    for (int i = 0; i < 8; i++) p[i] += __shfl_down(p[i], off);
  }
  int lane = d & 63, wv = d >> 6;
  if (lane == 0){
    #pragma unroll
    for (int i = 0; i < 8; i++) red[wv][i] = p[i];
  }
  __syncthreads();
  if (d < 8){
    float s = red[0][d] + red[1][d] + red[2][d] + red[3][d];
    int h = d & 3;
    if (d < 4) itb[(h*B_ + b)*T_ + t] = s + bi[h];
    else       ftb[(h*B_ + b)*T_ + t] = s + bfv[h];
  }
}

// ---------------- K3: MFMA GEMM for q,k,skip (A=qkb) and v,og (A=xinb) ----------------
// grid = 5 mats x 4 heads x 16 row-tiles (32 rows); block 256 = 4 waves (64 n-cols each)
__global__ __launch_bounds__(256) void k_gemm(
    const unsigned short* __restrict__ qkb, const unsigned short* __restrict__ xinb,
    const unsigned short* __restrict__ Wqt, const unsigned short* __restrict__ Wkt,
    const unsigned short* __restrict__ Wst, const unsigned short* __restrict__ Wvt,
    const unsigned short* __restrict__ Wot,
    const float* __restrict__ bq, const float* __restrict__ bk, const float* __restrict__ bsk,
    const float* __restrict__ bv, const float* __restrict__ bo,
    float* __restrict__ qo, float* __restrict__ ko, float* __restrict__ hb,
    float* __restrict__ vo, float* __restrict__ og){
  int bid = blockIdx.x;
  int rt  = bid & 15;
  int h   = (bid >> 4) & 3;
  int mat = bid >> 6;                    // 0=q 1=k 2=skip 3=v 4=og
  int tid = threadIdx.x;
  int w = tid >> 6, l = tid & 63;
  int lm = l & 15, lq = l >> 4;
  int r0 = rt * 32;
  const unsigned short* A = (mat < 3) ? (qkb + h*(TB_*D_)) : xinb;
  const unsigned short* Bt;
  const float* bias;
  float* out;
  switch (mat){
    case 0: Bt = Wqt; bias = bq;  out = qo; break;
    case 1: Bt = Wkt; bias = bk;  out = ko; break;
    case 2: Bt = Wst; bias = bsk; out = hb; break;
    case 3: Bt = Wvt; bias = bv;  out = vo; break;
    default: Bt = Wot; bias = bo; out = og; break;
  }
  Bt += h*(D_*D_);
  f32x4 acc[2][4];
  #pragma unroll
  for (int mt = 0; mt < 2; mt++)
    #pragma unroll
    for (int nt = 0; nt < 4; nt++) acc[mt][nt] = (f32x4){0.f,0.f,0.f,0.f};
  const unsigned short* Ap = A  + (r0 + lm)*D_ + lq*8;
  const unsigned short* Bp = Bt + (w*64 + lm)*D_ + lq*8;
  #pragma unroll
  for (int kc = 0; kc < 8; kc++){
    bf16x8 a0 = *(const bf16x8*)(Ap + kc*32);
    bf16x8 a1 = *(const bf16x8*)(Ap + 16*D_ + kc*32);
    bf16x8 b0 = *(const bf16x8*)(Bp + kc*32);
    bf16x8 b1 = *(const bf16x8*)(Bp + 16*D_ + kc*32);
    bf16x8 b2 = *(const bf16x8*)(Bp + 32*D_ + kc*32);
    bf16x8 b3 = *(const bf16x8*)(Bp + 48*D_ + kc*32);
    acc[0][0] = __builtin_amdgcn_mfma_f32_16x16x32_bf16(a0, b0, acc[0][0], 0, 0, 0);
    acc[0][1] = __builtin_amdgcn_mfma_f32_16x16x32_bf16(a0, b1, acc[0][1], 0, 0, 0);
    acc[0][2] = __builtin_amdgcn_mfma_f32_16x16x32_bf16(a0, b2, acc[0][2], 0, 0, 0);
    acc[0][3] = __builtin_amdgcn_mfma_f32_16x16x32_bf16(a0, b3, acc[0][3], 0, 0, 0);
    acc[1][0] = __builtin_amdgcn_mfma_f32_16x16x32_bf16(a1, b0, acc[1][0], 0, 0, 0);
    acc[1][1] = __builtin_amdgcn_mfma_f32_16x16x32_bf16(a1, b1, acc[1][1], 0, 0, 0);
    acc[1][2] = __builtin_amdgcn_mfma_f32_16x16x32_bf16(a1, b2, acc[1][2], 0, 0, 0);
    acc[1][3] = __builtin_amdgcn_mfma_f32_16x16x32_bf16(a1, b3, acc[1][3], 0, 0, 0);
  }
  float bval[4];
  #pragma unroll
  for (int nt = 0; nt < 4; nt++) bval[nt] = bias[h*D_ + w*64 + nt*16 + lm];
  #pragma unroll
  for (int mt = 0; mt < 2; mt++){
    #pragma unroll
    for (int r = 0; r < 4; r++){
      int row = r0 + mt*16 + lq*4 + r;
      int t = row >> 3, b = row & 7;
      int obase = (((t*NH_ + h)*B_ + b) << 8) + w*64 + lm;
      #pragma unroll
      for (int nt = 0; nt < 4; nt++){
        float vv = acc[mt][nt][r] + bval[nt];
        if (mat == 1) vv *= 0.0625f;        // * 1/sqrt(D)
        if (mat == 4) vv = sigm_(acc[mt][nt][r] + bval[nt]);
        out[obase + nt*16] = vv;
      }
    }
  }
}

// ---------------- K6: closed-form gate scan via wave prefix ops ----------------
__global__ void k_scan(const float* __restrict__ itb, const float* __restrict__ ftb,
                       float* __restrict__ colterm, float* __restrict__ rowbase){
  int id = blockIdx.x;                  // h*B + b  (32 blocks)
  int t = threadIdx.x;                  // 64 lanes = timesteps
  float ft = ftb[id*T_ + t];
  float it = itb[id*T_ + t];
  float F = ft;
  #pragma unroll
  for (int off = 1; off < 64; off <<= 1){
    float v2 = __shfl_up(F, off);
    if (t >= off) F += v2;
  }
  float ct = it - F;
  float G = ct;
  #pragma unroll
  for (int off = 1; off < 64; off <<= 1){
    float v2 = __shfl_up(G, off);
    if (t >= off) G = fmaxf(G, v2);
  }
  colterm[id*T_ + t] = ct;
  rowbase[id*T_ + t] = -fmaxf(0.f, G);
}

// ---------------- K7: masked decay attention, t-quarter per block ----------------
#define TQ_ 16
__global__ __launch_bounds__(256) void k_attn(
    const float* __restrict__ qo, const float* __restrict__ ko,
    const float* __restrict__ vo, const float* __restrict__ og,
    const float* __restrict__ colterm, const float* __restrict__ rowbase,
    float* __restrict__ hb){
  __shared__ float Qc[64*17];                  // [dd][tl] stride 17
  __shared__ float Kc[64*65];                  // [dd][s]  stride 65
  __shared__ __align__(16) float P2[64][20];   // [s][tl]
  __shared__ float scal[TQ_];
  int hbx = blockIdx.x >> 2;                   // h*B + b
  int tqi = blockIdx.x & 3;
  int t0  = tqi*TQ_;
  int tid = threadIdx.x;
  int hb_off = hbx << 8;
  const float* Qg = qo + hb_off;
  const float* Kg = ko + hb_off;
  int tg = tid >> 5, sg = tid & 31;
  float acc[2][2] = {{0.f,0.f},{0.f,0.f}};
  for (int c = 0; c < 4; c++){
    int d0 = c*64;
    for (int i = tid; i < TQ_*64; i += 256){
      int r = i >> 6, dd = i & 63;
      Qc[dd*17 + r] = Qg[(t0+r)*8192 + d0 + dd];
    }
    for (int i = tid; i < 64*64; i += 256){
      int s = i >> 6, dd = i & 63;
      Kc[dd*65 + s] = Kg[s*8192 + d0 + dd];
    }
    __syncthreads();
    for (int dd = 0; dd < 64; dd++){
      float q0 = Qc[dd*17 + tg*2], q1 = Qc[dd*17 + tg*2 + 1];
      float k0 = Kc[dd*65 + sg*2], k1 = Kc[dd*65 + sg*2 + 1];
      acc[0][0] = fmaf(q0, k0, acc[0][0]);
      acc[0][1] = fmaf(q0, k1, acc[0][1]);
      acc[1][0] = fmaf(q1, k0, acc[1][0]);
      acc[1][1] = fmaf(q1, k1, acc[1][1]);
    }
    __syncthreads();
  }
  const float* ct = colterm + hbx*T_;
  const float* rb = rowbase + hbx*T_;
  #pragma unroll
  for (int jt = 0; jt < 2; jt++){
    int tl = tg*2 + jt; int tglob = t0 + tl;
    float rbt = rb[tglob];
    #pragma unroll
    for (int js = 0; js < 2; js++){
      int s = sg*2 + js;
      float p = (s <= tglob) ? __expf(ct[s] + rbt) * acc[jt][js] : 0.f;
      P2[s][tl] = p;
    }
  }
  __syncthreads();
  if (tid < TQ_){
    float sum = 0.f;
    for (int s = 0; s < 64; s++) sum += P2[s][tid];
    scal[tid] = 1.0f / fmaxf(fabsf(sum), 1.0f);
  }
  __syncthreads();
  float ac[TQ_];
  #pragma unroll
  for (int i = 0; i < TQ_; i++) ac[i] = 0.f;
  const float* Vg = vo + hb_off + tid;
  for (int s = 0; s < 64; s++){
    float vv = Vg[s*8192];
    const float* pr = &P2[s][0];
    #pragma unroll
    for (int t4 = 0; t4 < 4; t4++){
      float4 pp = *(const float4*)(pr + t4*4);
      ac[t4*4+0] = fmaf(pp.x, vv, ac[t4*4+0]);
      ac[t4*4+1] = fmaf(pp.y, vv, ac[t4*4+1]);
      ac[t4*4+2] = fmaf(pp.z, vv, ac[t4*4+2]);
      ac[t4*4+3] = fmaf(pp.w, vv, ac[t4*4+3]);
    }
  }
  const float* Og = og + hb_off + tid;
  float* Hg = hb + hb_off + tid;
  #pragma unroll
  for (int tl = 0; tl < TQ_; tl++){
    int tglob = t0 + tl;
    Hg[tglob*8192] += Og[tglob*8192] * ac[tl] * scal[tl];
  }
}

// ---------------- K8: batchnorm over (nh,b)=32 per (t,d) + reshape ----------------
__global__ void k_bn2(const float* __restrict__ hbuf, const float* __restrict__ g,
                      const float* __restrict__ bb, float* __restrict__ ho){
  int id = blockIdx.x*256 + threadIdx.x;        // T*D
  int t = id >> 8, d = id & 255;
  float v[32]; float mu = 0.f;
  const float* hp = hbuf + ((t*NH_*B_) << 8) + d;
  #pragma unroll
  for (int i = 0; i < 32; i++){ v[i] = hp[i*D_]; mu += v[i]; }
  mu *= (1.0f/32.0f);
  float var = 0.f;
  #pragma unroll
  for (int i = 0; i < 32; i++){ float dd = v[i]-mu; var += dd*dd; }
  var *= (1.0f/32.0f);
  float sc = (1.0f/sqrtf(var + EPS_)) * g[d];
  float bs = bb[d];
  float* hop = ho + t*(B_*NH_*D_);
  #pragma unroll
  for (int i = 0; i < 32; i++){                 // i = h*B + b
    int hh = i >> 3, b = i & 7;
    hop[b*(NH_*D_) + hh*D_ + d] = (v[i]-mu)*sc + bs;
  }
}

// ---------------- K9: z = (ho @ Wpoll + bpoll) * trig ----------------
__global__ __launch_bounds__(256) void k_poll(
    const float* __restrict__ ho, const float* __restrict__ Wp,
    const float* __restrict__ bp, const float* __restrict__ trig,
    float* __restrict__ z){
  __shared__ __align__(16) float hos[4][NH_*D_];
  int rg = blockIdx.x >> 2;
  int cg = blockIdx.x & 3;
  int r0 = rg*4;
  int tid = threadIdx.x;
  #pragma unroll
  for (int r = 0; r < 4; r++){
    float4 v4 = *(const float4*)&ho[(r0+r)*(NH_*D_) + tid*4];
    *(float4*)&hos[r][tid*4] = v4;
  }
  __syncthreads();
  int tr = tid >> 6;
  int e  = (tid & 63) + cg*64;
  const float* wp = Wp + e;
  float acc = 0.f;
  for (int j = 0; j < NH_*D_; j += 4){
    float4 h4 = *(const float4*)&hos[tr][j];
    acc = fmaf(h4.x, wp[(j+0)*D_], acc);
    acc = fmaf(h4.y, wp[(j+1)*D_], acc);
    acc = fmaf(h4.z, wp[(j+2)*D_], acc);
    acc = fmaf(h4.w, wp[(j+3)*D_], acc);
  }
  int row = r0 + tr;
  z[row*D_ + e] = (acc + bp[e]) * trig[row*D_ + e];
}

// ---------------- K10: y = z @ Wdown + bdown + x ----------------
__global__ void k_down(const float* __restrict__ z, const float* __restrict__ Wd,
                       const float* __restrict__ bd, const float* __restrict__ x,
                       float* __restrict__ y){
  __shared__ float zs[2][D_];
  int r0 = blockIdx.x*2;
  int tid = threadIdx.x;
  for (int i = tid; i < 2*D_; i += 256){ zs[i >> 8][i & 255] = z[r0*D_ + i]; }
  __syncthreads();
  int r = tid >> 7, hh = tid & 127;
  float acc = 0.f;
  #pragma unroll 4
  for (int e = 0; e < D_; e++) acc = fmaf(zs[r][e], Wd[e*H_ + hh], acc);
  int row = r0 + r;
  y[row*H_ + hh] = acc + bd[hh] + x[row*H_ + hh];
}

extern "C" void kernel_launch(void* const* d_in, const int* in_sizes, int n_in,
                              void* d_out, int out_size, void* d_ws, size_t ws_size,
                              hipStream_t stream){
  const float* x     = (const float*)d_in[0];
  const float* Wq    = (const float*)d_in[1];
  const float* bq    = (const float*)d_in[2];
  const float* Wk    = (const float*)d_in[3];
  const float* bk    = (const float*)d_in[4];
  const float* Wv    = (const float*)d_in[5];
  const float* bv    = (const float*)d_in[6];
  const float* ck    = (const float*)d_in[7];
  const float* cb    = (const float*)d_in[8];
  const float* Wi    = (const float*)d_in[9];
  const float* bi    = (const float*)d_in[10];
  const float* Wf    = (const float*)d_in[11];
  const float* bf    = (const float*)d_in[12];
  const float* Wo    = (const float*)d_in[13];
  const float* bo    = (const float*)d_in[14];
  const float* Wsk   = (const float*)d_in[15];
  const float* bsk   = (const float*)d_in[16];
  const float* bn1s  = (const float*)d_in[17];
  const float* bn1b  = (const float*)d_in[18];
  const float* bn2s  = (const float*)d_in[19];
  const float* bn2b  = (const float*)d_in[20];
  const float* Wup1  = (const float*)d_in[21];
  const float* bup1  = (const float*)d_in[22];
  const float* Wup2  = (const float*)d_in[23];
  const float* bup2  = (const float*)d_in[24];
  const float* Wp    = (const float*)d_in[25];
  const float* bp    = (const float*)d_in[26];
  const float* Wd    = (const float*)d_in[27];
  const float* bd    = (const float*)d_in[28];
  float* y = (float*)d_out;

  float* w = (float*)d_ws;
  float* xin  = w;  w += T_*B_*D_;
  float* trig = w;  w += T_*B_*D_;
  float* qo   = w;  w += T_*NH_*B_*D_;
  float* ko   = w;  w += T_*NH_*B_*D_;
  float* vo   = w;  w += T_*NH_*B_*D_;
  float* og   = w;  w += T_*NH_*B_*D_;
  float* hbuf = w;  w += T_*NH_*B_*D_;
  float* itb  = w;  w += NH_*B_*T_;
  float* ftb  = w;  w += NH_*B_*T_;
  float* ctm  = w;  w += NH_*B_*T_;
  float* rbs  = w;  w += NH_*B_*T_;
  float* ho   = w;  w += T_*B_*NH_*D_;
  float* z    = w;  w += T_*B_*D_;
  unsigned short* xinb = (unsigned short*)w;  w += (T_*B_*D_)/2;
  unsigned short* qkb  = (unsigned short*)w;  w += (NH_*TB_*D_)/2;
  unsigned short* Wqt  = (unsigned short*)w;  w += (NH_*D_*D_)/2;
  unsigned short* Wkt  = (unsigned short*)w;  w += (NH_*D_*D_)/2;
  unsigned short* Wst  = (unsigned short*)w;  w += (NH_*D_*D_)/2;
  unsigned short* Wvt  = (unsigned short*)w;  w += (NH_*D_*D_)/2;
  unsigned short* Wot  = (unsigned short*)w;  w += (NH_*D_*D_)/2;

  k_cvtw <<<320, 256, 0, stream>>>(Wq, Wk, Wsk, Wv, Wo, Wqt, Wkt, Wst, Wvt, Wot);
  k_front<<<T_*4, 256, 0, stream>>>(x, bn1s, bn1b, Wup1, bup1, Wup2, bup2, xin, xinb, trig);
  k_cg   <<<TB_, 256, 0, stream>>>(xin, ck, cb, Wi, bi, Wf, bf, qkb, itb, ftb);
  k_gemm <<<320, 256, 0, stream>>>(qkb, xinb, Wqt, Wkt, Wst, Wvt, Wot,
                                   bq, bk, bsk, bv, bo, qo, ko, hbuf, vo, og);
  k_scan <<<NH_*B_, 64, 0, stream>>>(itb, ftb, ctm, rbs);
  k_attn <<<NH_*B_*4, 256, 0, stream>>>(qo, ko, vo, og, ctm, rbs, hbuf);
  k_bn2  <<<(T_*D_)/256, 256, 0, stream>>>(hbuf, bn2s, bn2b, ho);
  k_poll <<<128*4, 256, 0, stream>>>(ho, Wp, bp, trig, z);
  k_down <<<TB_/2, 256, 0, stream>>>(z, Wd, bd, x, y);
}

// Round 4
// 200.701 us; speedup vs baseline: 1.6292x; 1.0352x over previous
//
#include <hip/hip_runtime.h>
#include <hip/hip_bf16.h>

#define T_ 64
#define B_ 8
#define H_ 128
#define NH_ 4
#define D_ 256
#define TB_ 512          // T_*B_
#define EPS_ 1e-5f

typedef short bf16x8 __attribute__((ext_vector_type(8)));
typedef float f32x4 __attribute__((ext_vector_type(4)));

__device__ __forceinline__ float silu_(float x){ return x / (1.0f + __expf(-x)); }
__device__ __forceinline__ float sigm_(float x){ return 1.0f / (1.0f + __expf(-x)); }
__device__ __forceinline__ unsigned short tobf_(float f){
  unsigned u = __float_as_uint(f);
  u += 0x7FFF + ((u >> 16) & 1);          // round-to-nearest-even
  return (unsigned short)(u >> 16);
}
// A-fragment-linear address for element (m, k) of a [M x 256] bf16 matrix:
// tile=(m>>4), lane=((k>>3)&3)*16 + (m&15), kb=k>>5, j=k&7
__device__ __forceinline__ int afrag_(int m, int k){
  return (((m >> 4)*8 + (k >> 5))*64 + ((k >> 3)&3)*16 + (m & 15))*8 + (k & 7);
}

// ---------------- K0: convert 5 weight tensors to bf16 fragment-linear B layout ----------------
// B[n][k] = W[k][n]; frag addr with m->n. grid = 5 mats x 4 heads x 32; block 256
__global__ __launch_bounds__(256) void k_cvtw(
    const float* __restrict__ Wq, const float* __restrict__ Wk, const float* __restrict__ Ws,
    const float* __restrict__ Wv, const float* __restrict__ Wo,
    unsigned short* __restrict__ Wqt, unsigned short* __restrict__ Wkt,
    unsigned short* __restrict__ Wst, unsigned short* __restrict__ Wvt,
    unsigned short* __restrict__ Wot){
  int bid = blockIdx.x;
  int sub = bid & 31;            // 32 blocks per (mat,head)
  int h   = (bid >> 5) & 3;
  int mat = bid >> 7;
  const float* Win; unsigned short* Wout;
  switch (mat){
    case 0: Win = Wq; Wout = Wqt; break;
    case 1: Win = Wk; Wout = Wkt; break;
    case 2: Win = Ws; Wout = Wst; break;
    case 3: Win = Wv; Wout = Wvt; break;
    default: Win = Wo; Wout = Wot; break;
  }
  Win  += h * (D_*D_);
  Wout += h * (D_*D_);
  int gid = sub*256 + threadIdx.x;     // 8192 threads per (mat,head)
  int combo = gid >> 6;                // (nt*8 + kb), 0..127
  int l = gid & 63;
  int lm = l & 15, lq = l >> 4;
  int nt = combo >> 3, kb = combo & 7;
  int n = nt*16 + lm;
  int k0 = kb*32 + lq*8;
  bf16x8 v;
  #pragma unroll
  for (int j = 0; j < 8; j++) v[j] = (short)tobf_(Win[(k0+j)*D_ + n]);
  *(bf16x8*)(Wout + (combo*64 + l)*8) = v;
}

// ---------------- K1: bn1 + up-proj; grid = T x 4 e-quarters, 8 rows/block ----------------
__global__ __launch_bounds__(256) void k_front(
    const float* __restrict__ x, const float* __restrict__ bn1s, const float* __restrict__ bn1b,
    const float* __restrict__ W1, const float* __restrict__ b1,
    const float* __restrict__ W2, const float* __restrict__ b2,
    float* __restrict__ xin, unsigned short* __restrict__ xinb, float* __restrict__ trig){
  __shared__ float us[H_][8];
  int t = blockIdx.x >> 2, eq = blockIdx.x & 3;
  int tid = threadIdx.x;
  if (tid < H_){
    const float* xp = x + t*(B_*H_) + tid;
    float v0[8]; float mu = 0.f;
    #pragma unroll
    for (int b = 0; b < 8; b++){ v0[b] = xp[b*H_]; mu += v0[b]; }
    mu *= 0.125f;
    float var = 0.f;
    #pragma unroll
    for (int b = 0; b < 8; b++){ float dd = v0[b]-mu; var += dd*dd; }
    var *= 0.125f;
    float sc = (1.0f/sqrtf(var + EPS_)) * bn1s[tid];
    float bs = bn1b[tid];
    #pragma unroll
    for (int b = 0; b < 8; b++) us[tid][b] = (v0[b]-mu)*sc + bs;
  }
  __syncthreads();
  int e_l = tid & 63, rg = tid >> 6;        // rg = wave id; rows rg*2, rg*2+1
  int e = eq*64 + e_l;
  float a10 = 0.f, a11 = 0.f, a20 = 0.f, a21 = 0.f;
  const float* w1p = W1 + e;
  const float* w2p = W2 + e;
  #pragma unroll 4
  for (int hh = 0; hh < H_; hh++){
    float w1v = w1p[hh*D_], w2v = w2p[hh*D_];
    float u0 = us[hh][rg*2], u1 = us[hh][rg*2+1];
    a10 = fmaf(u0, w1v, a10); a11 = fmaf(u1, w1v, a11);
    a20 = fmaf(u0, w2v, a20); a21 = fmaf(u1, w2v, a21);
  }
  float be1 = b1[e], be2 = b2[e];
  int row0 = t*B_ + rg*2;
  float vA = a10 + be1, vB = a11 + be1;
  xin[row0*D_ + e] = vA;        xin[(row0+1)*D_ + e] = vB;
  int fa = afrag_(row0, e);
  xinb[fa]     = tobf_(vA);
  xinb[fa + 8] = tobf_(vB);     // row0+1 -> lm+1 -> +8 elements
  trig[row0*D_ + e] = silu_(a20 + be2);
  trig[(row0+1)*D_ + e] = silu_(a21 + be2);
}

// ---------------- K2: depthwise conv + silu (-> qkb A-frag per head) + gate dots ----------------
__global__ __launch_bounds__(256) void k_cg(
    const float* __restrict__ xin, const float* __restrict__ ck, const float* __restrict__ cb,
    const float* __restrict__ Wi, const float* __restrict__ bi,
    const float* __restrict__ Wf, const float* __restrict__ bfv,
    unsigned short* __restrict__ qkb, float* __restrict__ itb, float* __restrict__ ftb){
  __shared__ float xs[D_];
  __shared__ float red[4][8];
  int row = blockIdx.x;                 // t*B + b
  int t = row >> 3, b = row & 7;
  int d = threadIdx.x;
  float xv = xin[row*D_ + d];
  xs[d] = xv;
  __syncthreads();
  float xm1 = (d >= 1)   ? xs[d-1] : 0.f;
  float xp1 = (d <= 254) ? xs[d+1] : 0.f;
  float xp2 = (d <= 253) ? xs[d+2] : 0.f;
  int fa = afrag_(row, d);
  #pragma unroll
  for (int h = 0; h < NH_; h++){
    float acc = cb[h];
    acc = fmaf(xm1, ck[0*NH_+h], acc);
    acc = fmaf(xv,  ck[1*NH_+h], acc);
    acc = fmaf(xp1, ck[2*NH_+h], acc);
    acc = fmaf(xp2, ck[3*NH_+h], acc);
    qkb[h*(TB_*D_) + fa] = tobf_(silu_(acc));
  }
  float p[8];
  #pragma unroll
  for (int h = 0; h < NH_; h++){
    p[h]   = xv * Wi[h*D_ + d];
    p[4+h] = xv * Wf[h*D_ + d];
  }
  #pragma unroll
  for (int off = 32; off >= 1; off >>= 1){
    #pragma unroll
    for (int i = 0; i < 8; i++) p[i] += __shfl_down(p[i], off);
  }
  int lane = d & 63, wv = d >> 6;
  if (lane == 0){
    #pragma unroll
    for (int i = 0; i < 8; i++) red[wv][i] = p[i];
  }
  __syncthreads();
  if (d < 8){
    float s = red[0][d] + red[1][d] + red[2][d] + red[3][d];
    int h = d & 3;
    if (d < 4) itb[(h*B_ + b)*T_ + t] = s + bi[h];
    else       ftb[(h*B_ + b)*T_ + t] = s + bfv[h];
  }
}

// ---------------- K3: MFMA GEMM, all operands fragment-linear (fully coalesced) ----------------
// grid = 5 mats x 4 heads x 16 row-tiles (32 rows); block 256 = 4 waves (64 n-cols each)
__global__ __launch_bounds__(256) void k_gemm(
    const unsigned short* __restrict__ qkb, const unsigned short* __restrict__ xinb,
    const unsigned short* __restrict__ Wqt, const unsigned short* __restrict__ Wkt,
    const unsigned short* __restrict__ Wst, const unsigned short* __restrict__ Wvt,
    const unsigned short* __restrict__ Wot,
    const float* __restrict__ bq, const float* __restrict__ bk, const float* __restrict__ bsk,
    const float* __restrict__ bv, const float* __restrict__ bo,
    float* __restrict__ qo, float* __restrict__ ko, float* __restrict__ hb,
    float* __restrict__ vo, float* __restrict__ og){
  int bid = blockIdx.x;
  int rt  = bid & 15;
  int h   = (bid >> 4) & 3;
  int mat = bid >> 6;                    // 0=q 1=k 2=skip 3=v 4=og
  int tid = threadIdx.x;
  int w = tid >> 6, l = tid & 63;
  int lm = l & 15, lq = l >> 4;
  int r0 = rt * 32;
  const unsigned short* A = (mat < 3) ? (qkb + h*(TB_*D_)) : xinb;
  const unsigned short* Bt;
  const float* bias;
  float* out;
  switch (mat){
    case 0: Bt = Wqt; bias = bq;  out = qo; break;
    case 1: Bt = Wkt; bias = bk;  out = ko; break;
    case 2: Bt = Wst; bias = bsk; out = hb; break;
    case 3: Bt = Wvt; bias = bv;  out = vo; break;
    default: Bt = Wot; bias = bo; out = og; break;
  }
  Bt += h*(D_*D_);
  f32x4 acc[2][4];
  #pragma unroll
  for (int mt = 0; mt < 2; mt++)
    #pragma unroll
    for (int nt = 0; nt < 4; nt++) acc[mt][nt] = (f32x4){0.f,0.f,0.f,0.f};
  const unsigned short* Ap = A + l*8;
  const unsigned short* Bp = Bt + l*8;
  #pragma unroll
  for (int kc = 0; kc < 8; kc++){
    bf16x8 a0 = *(const bf16x8*)(Ap + ((rt*16      + kc) << 9));
    bf16x8 a1 = *(const bf16x8*)(Ap + ((rt*16 + 8  + kc) << 9));
    bf16x8 b0 = *(const bf16x8*)(Bp + (((w*4+0)*8 + kc) << 9));
    bf16x8 b1 = *(const bf16x8*)(Bp + (((w*4+1)*8 + kc) << 9));
    bf16x8 b2 = *(const bf16x8*)(Bp + (((w*4+2)*8 + kc) << 9));
    bf16x8 b3 = *(const bf16x8*)(Bp + (((w*4+3)*8 + kc) << 9));
    acc[0][0] = __builtin_amdgcn_mfma_f32_16x16x32_bf16(a0, b0, acc[0][0], 0, 0, 0);
    acc[0][1] = __builtin_amdgcn_mfma_f32_16x16x32_bf16(a0, b1, acc[0][1], 0, 0, 0);
    acc[0][2] = __builtin_amdgcn_mfma_f32_16x16x32_bf16(a0, b2, acc[0][2], 0, 0, 0);
    acc[0][3] = __builtin_amdgcn_mfma_f32_16x16x32_bf16(a0, b3, acc[0][3], 0, 0, 0);
    acc[1][0] = __builtin_amdgcn_mfma_f32_16x16x32_bf16(a1, b0, acc[1][0], 0, 0, 0);
    acc[1][1] = __builtin_amdgcn_mfma_f32_16x16x32_bf16(a1, b1, acc[1][1], 0, 0, 0);
    acc[1][2] = __builtin_amdgcn_mfma_f32_16x16x32_bf16(a1, b2, acc[1][2], 0, 0, 0);
    acc[1][3] = __builtin_amdgcn_mfma_f32_16x16x32_bf16(a1, b3, acc[1][3], 0, 0, 0);
  }
  float bval[4];
  #pragma unroll
  for (int nt = 0; nt < 4; nt++) bval[nt] = bias[h*D_ + w*64 + nt*16 + lm];
  #pragma unroll
  for (int mt = 0; mt < 2; mt++){
    #pragma unroll
    for (int r = 0; r < 4; r++){
      int row = r0 + mt*16 + lq*4 + r;
      int t = row >> 3, b = row & 7;
      int obase = (((t*NH_ + h)*B_ + b) << 8) + w*64 + lm;
      #pragma unroll
      for (int nt = 0; nt < 4; nt++){
        float vv = acc[mt][nt][r] + bval[nt];
        if (mat == 1) vv *= 0.0625f;        // * 1/sqrt(D)
        if (mat == 4) vv = sigm_(acc[mt][nt][r] + bval[nt]);
        out[obase + nt*16] = vv;
      }
    }
  }
}

// ---------------- K7: masked decay attention (gate scan fused in wave 0) ----------------
#define TQ_ 16
__global__ __launch_bounds__(256) void k_attn(
    const float* __restrict__ qo, const float* __restrict__ ko,
    const float* __restrict__ vo, const float* __restrict__ og,
    const float* __restrict__ itb, const float* __restrict__ ftb,
    float* __restrict__ hb){
  __shared__ float Qc[64*17];                  // [dd][tl] stride 17
  __shared__ float Kc[64*65];                  // [dd][s]  stride 65
  __shared__ __align__(16) float P2[64][20];   // [s][tl]
  __shared__ float scal[TQ_];
  __shared__ float ctS[64], rbS[64];
  int hbx = blockIdx.x >> 2;                   // h*B + b
  int tqi = blockIdx.x & 3;
  int t0  = tqi*TQ_;
  int tid = threadIdx.x;
  int hb_off = hbx << 8;
  // fused closed-form gate scan (wave 0): F_t = prefix-sum ft; ct_s = it_s - F_s;
  // rb_t = -max(0, prefix-max ct)
  if (tid < 64){
    float F = ftb[hbx*T_ + tid];
    float it = itb[hbx*T_ + tid];
    #pragma unroll
    for (int off = 1; off < 64; off <<= 1){
      float v2 = __shfl_up(F, off);
      if (tid >= off) F += v2;
    }
    float ct = it - F;
    float G = ct;
    #pragma unroll
    for (int off = 1; off < 64; off <<= 1){
      float v2 = __shfl_up(G, off);
      if (tid >= off) G = fmaxf(G, v2);
    }
    ctS[tid] = ct;
    rbS[tid] = -fmaxf(0.f, G);
  }
  const float* Qg = qo + hb_off;
  const float* Kg = ko + hb_off;
  int tg = tid >> 5, sg = tid & 31;
  float acc[2][2] = {{0.f,0.f},{0.f,0.f}};
  for (int c = 0; c < 4; c++){
    int d0 = c*64;
    for (int i = tid; i < TQ_*64; i += 256){
      int r = i >> 6, dd = i & 63;
      Qc[dd*17 + r] = Qg[(t0+r)*8192 + d0 + dd];
    }
    for (int i = tid; i < 64*64; i += 256){
      int s = i >> 6, dd = i & 63;
      Kc[dd*65 + s] = Kg[s*8192 + d0 + dd];
    }
    __syncthreads();
    for (int dd = 0; dd < 64; dd++){
      float q0 = Qc[dd*17 + tg*2], q1 = Qc[dd*17 + tg*2 + 1];
      float k0 = Kc[dd*65 + sg*2], k1 = Kc[dd*65 + sg*2 + 1];
      acc[0][0] = fmaf(q0, k0, acc[0][0]);
      acc[0][1] = fmaf(q0, k1, acc[0][1]);
      acc[1][0] = fmaf(q1, k0, acc[1][0]);
      acc[1][1] = fmaf(q1, k1, acc[1][1]);
    }
    __syncthreads();
  }
  #pragma unroll
  for (int jt = 0; jt < 2; jt++){
    int tl = tg*2 + jt; int tglob = t0 + tl;
    float rbt = rbS[tglob];
    #pragma unroll
    for (int js = 0; js < 2; js++){
      int s = sg*2 + js;
      float p = (s <= tglob) ? __expf(ctS[s] + rbt) * acc[jt][js] : 0.f;
      P2[s][tl] = p;
    }
  }
  __syncthreads();
  if (tid < TQ_){
    float sum = 0.f;
    for (int s = 0; s < 64; s++) sum += P2[s][tid];
    scal[tid] = 1.0f / fmaxf(fabsf(sum), 1.0f);
  }
  __syncthreads();
  float ac[TQ_];
  #pragma unroll
  for (int i = 0; i < TQ_; i++) ac[i] = 0.f;
  const float* Vg = vo + hb_off + tid;
  for (int s = 0; s < 64; s++){
    float vv = Vg[s*8192];
    const float* pr = &P2[s][0];
    #pragma unroll
    for (int t4 = 0; t4 < 4; t4++){
      float4 pp = *(const float4*)(pr + t4*4);
      ac[t4*4+0] = fmaf(pp.x, vv, ac[t4*4+0]);
      ac[t4*4+1] = fmaf(pp.y, vv, ac[t4*4+1]);
      ac[t4*4+2] = fmaf(pp.z, vv, ac[t4*4+2]);
      ac[t4*4+3] = fmaf(pp.w, vv, ac[t4*4+3]);
    }
  }
  const float* Og = og + hb_off + tid;
  float* Hg = hb + hb_off + tid;
  #pragma unroll
  for (int tl = 0; tl < TQ_; tl++){
    int tglob = t0 + tl;
    Hg[tglob*8192] += Og[tglob*8192] * ac[tl] * scal[tl];
  }
}

// ---------------- K8: batchnorm over (nh,b)=32 per (t,d) + reshape ----------------
__global__ void k_bn2(const float* __restrict__ hbuf, const float* __restrict__ g,
                      const float* __restrict__ bb, float* __restrict__ ho){
  int id = blockIdx.x*256 + threadIdx.x;        // T*D
  int t = id >> 8, d = id & 255;
  float v[32]; float mu = 0.f;
  const float* hp = hbuf + ((t*NH_*B_) << 8) + d;
  #pragma unroll
  for (int i = 0; i < 32; i++){ v[i] = hp[i*D_]; mu += v[i]; }
  mu *= (1.0f/32.0f);
  float var = 0.f;
  #pragma unroll
  for (int i = 0; i < 32; i++){ float dd = v[i]-mu; var += dd*dd; }
  var *= (1.0f/32.0f);
  float sc = (1.0f/sqrtf(var + EPS_)) * g[d];
  float bs = bb[d];
  float* hop = ho + t*(B_*NH_*D_);
  #pragma unroll
  for (int i = 0; i < 32; i++){                 // i = h*B + b
    int hh = i >> 3, b = i & 7;
    hop[b*(NH_*D_) + hh*D_ + d] = (v[i]-mu)*sc + bs;
  }
}

// ---------------- K9: z = (ho @ Wpoll + bpoll) * trig ----------------
__global__ __launch_bounds__(256) void k_poll(
    const float* __restrict__ ho, const float* __restrict__ Wp,
    const float* __restrict__ bp, const float* __restrict__ trig,
    float* __restrict__ z){
  __shared__ __align__(16) float hos[4][NH_*D_];
  int rg = blockIdx.x >> 2;
  int cg = blockIdx.x & 3;
  int r0 = rg*4;
  int tid = threadIdx.x;
  #pragma unroll
  for (int r = 0; r < 4; r++){
    float4 v4 = *(const float4*)&ho[(r0+r)*(NH_*D_) + tid*4];
    *(float4*)&hos[r][tid*4] = v4;
  }
  __syncthreads();
  int tr = tid >> 6;
  int e  = (tid & 63) + cg*64;
  const float* wp = Wp + e;
  float acc = 0.f;
  for (int j = 0; j < NH_*D_; j += 4){
    float4 h4 = *(const float4*)&hos[tr][j];
    acc = fmaf(h4.x, wp[(j+0)*D_], acc);
    acc = fmaf(h4.y, wp[(j+1)*D_], acc);
    acc = fmaf(h4.z, wp[(j+2)*D_], acc);
    acc = fmaf(h4.w, wp[(j+3)*D_], acc);
  }
  int row = r0 + tr;
  z[row*D_ + e] = (acc + bp[e]) * trig[row*D_ + e];
}

// ---------------- K10: y = z @ Wdown + bdown + x ----------------
__global__ void k_down(const float* __restrict__ z, const float* __restrict__ Wd,
                       const float* __restrict__ bd, const float* __restrict__ x,
                       float* __restrict__ y){
  __shared__ float zs[2][D_];
  int r0 = blockIdx.x*2;
  int tid = threadIdx.x;
  for (int i = tid; i < 2*D_; i += 256){ zs[i >> 8][i & 255] = z[r0*D_ + i]; }
  __syncthreads();
  int r = tid >> 7, hh = tid & 127;
  float acc = 0.f;
  #pragma unroll 4
  for (int e = 0; e < D_; e++) acc = fmaf(zs[r][e], Wd[e*H_ + hh], acc);
  int row = r0 + r;
  y[row*H_ + hh] = acc + bd[hh] + x[row*H_ + hh];
}

extern "C" void kernel_launch(void* const* d_in, const int* in_sizes, int n_in,
                              void* d_out, int out_size, void* d_ws, size_t ws_size,
                              hipStream_t stream){
  const float* x     = (const float*)d_in[0];
  const float* Wq    = (const float*)d_in[1];
  const float* bq    = (const float*)d_in[2];
  const float* Wk    = (const float*)d_in[3];
  const float* bk    = (const float*)d_in[4];
  const float* Wv    = (const float*)d_in[5];
  const float* bv    = (const float*)d_in[6];
  const float* ck    = (const float*)d_in[7];
  const float* cb    = (const float*)d_in[8];
  const float* Wi    = (const float*)d_in[9];
  const float* bi    = (const float*)d_in[10];
  const float* Wf    = (const float*)d_in[11];
  const float* bf    = (const float*)d_in[12];
  const float* Wo    = (const float*)d_in[13];
  const float* bo    = (const float*)d_in[14];
  const float* Wsk   = (const float*)d_in[15];
  const float* bsk   = (const float*)d_in[16];
  const float* bn1s  = (const float*)d_in[17];
  const float* bn1b  = (const float*)d_in[18];
  const float* bn2s  = (const float*)d_in[19];
  const float* bn2b  = (const float*)d_in[20];
  const float* Wup1  = (const float*)d_in[21];
  const float* bup1  = (const float*)d_in[22];
  const float* Wup2  = (const float*)d_in[23];
  const float* bup2  = (const float*)d_in[24];
  const float* Wp    = (const float*)d_in[25];
  const float* bp    = (const float*)d_in[26];
  const float* Wd    = (const float*)d_in[27];
  const float* bd    = (const float*)d_in[28];
  float* y = (float*)d_out;

  float* w = (float*)d_ws;
  float* xin  = w;  w += T_*B_*D_;
  float* trig = w;  w += T_*B_*D_;
  float* qo   = w;  w += T_*NH_*B_*D_;
  float* ko   = w;  w += T_*NH_*B_*D_;
  float* vo   = w;  w += T_*NH_*B_*D_;
  float* og   = w;  w += T_*NH_*B_*D_;
  float* hbuf = w;  w += T_*NH_*B_*D_;
  float* itb  = w;  w += NH_*B_*T_;
  float* ftb  = w;  w += NH_*B_*T_;
  float* ho   = w;  w += T_*B_*NH_*D_;
  float* z    = w;  w += T_*B_*D_;
  unsigned short* xinb = (unsigned short*)w;  w += (T_*B_*D_)/2;
  unsigned short* qkb  = (unsigned short*)w;  w += (NH_*TB_*D_)/2;
  unsigned short* Wqt  = (unsigned short*)w;  w += (NH_*D_*D_)/2;
  unsigned short* Wkt  = (unsigned short*)w;  w += (NH_*D_*D_)/2;
  unsigned short* Wst  = (unsigned short*)w;  w += (NH_*D_*D_)/2;
  unsigned short* Wvt  = (unsigned short*)w;  w += (NH_*D_*D_)/2;
  unsigned short* Wot  = (unsigned short*)w;  w += (NH_*D_*D_)/2;

  k_cvtw <<<640, 256, 0, stream>>>(Wq, Wk, Wsk, Wv, Wo, Wqt, Wkt, Wst, Wvt, Wot);
  k_front<<<T_*4, 256, 0, stream>>>(x, bn1s, bn1b, Wup1, bup1, Wup2, bup2, xin, xinb, trig);
  k_cg   <<<TB_, 256, 0, stream>>>(xin, ck, cb, Wi, bi, Wf, bf, qkb, itb, ftb);
  k_gemm <<<320, 256, 0, stream>>>(qkb, xinb, Wqt, Wkt, Wst, Wvt, Wot,
                                   bq, bk, bsk, bv, bo, qo, ko, hbuf, vo, og);
  k_attn <<<NH_*B_*4, 256, 0, stream>>>(qo, ko, vo, og, itb, ftb, hbuf);
  k_bn2  <<<(T_*D_)/256, 256, 0, stream>>>(hbuf, bn2s, bn2b, ho);
  k_poll <<<128*4, 256, 0, stream>>>(ho, Wp, bp, trig, z);
  k_down <<<TB_/2, 256, 0, stream>>>(z, Wd, bd, x, y);
}

// Round 5
// 187.696 us; speedup vs baseline: 1.7421x; 1.0693x over previous
//
#include <hip/hip_runtime.h>
#include <hip/hip_bf16.h>

#define T_ 64
#define B_ 8
#define H_ 128
#define NH_ 4
#define D_ 256
#define TB_ 512          // T_*B_
#define EPS_ 1e-5f

typedef short bf16x8 __attribute__((ext_vector_type(8)));
typedef float f32x4 __attribute__((ext_vector_type(4)));

__device__ __forceinline__ float silu_(float x){ return x / (1.0f + __expf(-x)); }
__device__ __forceinline__ float sigm_(float x){ return 1.0f / (1.0f + __expf(-x)); }
__device__ __forceinline__ unsigned short tobf_(float f){
  unsigned u = __float_as_uint(f);
  u += 0x7FFF + ((u >> 16) & 1);          // round-to-nearest-even
  return (unsigned short)(u >> 16);
}
// A-fragment-linear address, element (m,k) of [M x 256] bf16 matrix
__device__ __forceinline__ int afrag_(int m, int k){
  return (((m >> 4)*8 + (k >> 5))*64 + ((k >> 3)&3)*16 + (m & 15))*8 + (k & 7);
}

// ---------------- K1: all weight conversions + bn1 + u (A-frag bf16) ----------------
// blocks 0..639: Wq/Wk/Ws/Wv/Wo -> B-frag; 640..671: Wup1/Wup2 -> B-frag (K=128);
// 672..703: bn1 -> u A-frag (K=128)
__global__ __launch_bounds__(256) void k_prep(
    const float* __restrict__ Wq, const float* __restrict__ Wk, const float* __restrict__ Ws,
    const float* __restrict__ Wv, const float* __restrict__ Wo,
    const float* __restrict__ Wup1, const float* __restrict__ Wup2,
    const float* __restrict__ x, const float* __restrict__ bn1s, const float* __restrict__ bn1b,
    unsigned short* __restrict__ Wqt, unsigned short* __restrict__ Wkt,
    unsigned short* __restrict__ Wst, unsigned short* __restrict__ Wvt,
    unsigned short* __restrict__ Wot,
    unsigned short* __restrict__ Wu1t, unsigned short* __restrict__ Wu2t,
    unsigned short* __restrict__ ub){
  int bid = blockIdx.x;
  int tid = threadIdx.x;
  if (bid < 640){
    int sub = bid & 31;
    int h   = (bid >> 5) & 3;
    int mat = bid >> 7;
    const float* Win; unsigned short* Wout;
    switch (mat){
      case 0: Win = Wq; Wout = Wqt; break;
      case 1: Win = Wk; Wout = Wkt; break;
      case 2: Win = Ws; Wout = Wst; break;
      case 3: Win = Wv; Wout = Wvt; break;
      default: Win = Wo; Wout = Wot; break;
    }
    Win  += h * (D_*D_);
    Wout += h * (D_*D_);
    int gid = sub*256 + tid;
    int combo = gid >> 6;                // nt*8 + kb
    int l = gid & 63;
    int lm = l & 15, lq = l >> 4;
    int nt = combo >> 3, kb = combo & 7;
    int n = nt*16 + lm;
    int k0 = kb*32 + lq*8;
    bf16x8 v;
    #pragma unroll
    for (int j = 0; j < 8; j++) v[j] = (short)tobf_(Win[(k0+j)*D_ + n]);
    *(bf16x8*)(Wout + (combo*64 + l)*8) = v;
  } else if (bid < 672){
    int idx = bid - 640;
    const float* Win = (idx < 16) ? Wup1 : Wup2;
    unsigned short* Wout = (idx < 16) ? Wu1t : Wu2t;
    int sub = idx & 15;
    int gid = sub*256 + tid;             // [0,4096)
    int combo = gid >> 6;                // nt*4 + kb  (kb over K=128)
    int l = gid & 63;
    int lm = l & 15, lq = l >> 4;
    int nt = combo >> 2, kb = combo & 3;
    int n = nt*16 + lm;
    int k0 = kb*32 + lq*8;
    bf16x8 v;
    #pragma unroll
    for (int j = 0; j < 8; j++) v[j] = (short)tobf_(Win[(k0+j)*D_ + n]);
    *(bf16x8*)(Wout + (combo*64 + l)*8) = v;
  } else {
    int i = bid - 672;                   // m-tile 0..31 (rows 16i..16i+15)
    int tt = tid >> 7, hf = tid & 127;
    int t = i*2 + tt;
    const float* xp = x + t*(B_*H_) + hf;
    float v0[8]; float mu = 0.f;
    #pragma unroll
    for (int b = 0; b < 8; b++){ v0[b] = xp[b*H_]; mu += v0[b]; }
    mu *= 0.125f;
    float var = 0.f;
    #pragma unroll
    for (int b = 0; b < 8; b++){ float dd = v0[b]-mu; var += dd*dd; }
    var *= 0.125f;
    float sc = (1.0f/sqrtf(var + EPS_)) * bn1s[hf];
    float bs = bn1b[hf];
    int kb = hf >> 5, j = hf & 7;
    int lanebase = ((hf >> 3)&3)*16 + tt*8;
    unsigned short* up = ub + ((i*4 + kb)*64)*8 + j;
    #pragma unroll
    for (int b = 0; b < 8; b++)
      up[(lanebase + b)*8] = tobf_((v0[b]-mu)*sc + bs);
  }
}

// ---------------- K2: up-proj MFMA GEMM + fused conv/gates (mat0) / trig (mat1) ----------------
// grid 64: mat = bid>>5 (0: Wup1->xin, 1: Wup2->trig), rt = bid&31 (16-row tile)
__global__ __launch_bounds__(256) void k_upcg(
    const unsigned short* __restrict__ ub,
    const unsigned short* __restrict__ Wu1t, const unsigned short* __restrict__ Wu2t,
    const float* __restrict__ bup1, const float* __restrict__ bup2,
    const float* __restrict__ ck, const float* __restrict__ cb,
    const float* __restrict__ Wi, const float* __restrict__ bi,
    const float* __restrict__ Wf, const float* __restrict__ bfv,
    unsigned short* __restrict__ xinb, unsigned short* __restrict__ qkb,
    float* __restrict__ trig, float* __restrict__ itb, float* __restrict__ ftb){
  __shared__ float xs[16][257];         // stride 257: conv conflict-free, gates 4-way max
  int bid = blockIdx.x;
  int mat = bid >> 5, rt = bid & 31;
  int tid = threadIdx.x;
  int w = tid >> 6, l = tid & 63, lm = l & 15, lq = l >> 4;
  const unsigned short* Bt = (mat == 0) ? Wu1t : Wu2t;
  f32x4 acc[4];
  #pragma unroll
  for (int nt = 0; nt < 4; nt++) acc[nt] = (f32x4){0.f,0.f,0.f,0.f};
  const unsigned short* Ap = ub + l*8;
  const unsigned short* Bp = Bt + l*8;
  #pragma unroll
  for (int kb = 0; kb < 4; kb++){
    bf16x8 a = *(const bf16x8*)(Ap + ((rt*4 + kb) << 9));
    #pragma unroll
    for (int nt = 0; nt < 4; nt++){
      bf16x8 bfr = *(const bf16x8*)(Bp + (((w*4+nt)*4 + kb) << 9));
      acc[nt] = __builtin_amdgcn_mfma_f32_16x16x32_bf16(a, bfr, acc[nt], 0, 0, 0);
    }
  }
  const float* bias = (mat == 0) ? bup1 : bup2;
  #pragma unroll
  for (int nt = 0; nt < 4; nt++){
    #pragma unroll
    for (int r = 0; r < 4; r++){
      int m = lq*4 + r;
      int row = rt*16 + m;
      int e = w*64 + nt*16 + lm;
      float vv = acc[nt][r] + bias[e];
      if (mat == 1){
        trig[row*D_ + e] = silu_(vv);
      } else {
        xinb[afrag_(row, e)] = tobf_(vv);
        xs[m][e] = vv;
      }
    }
  }
  if (mat == 0){
    __syncthreads();
    // depthwise conv k=4 (pad 1 left, 2 right) + silu -> qkb A-frag per head
    int d = tid;
    #pragma unroll 4
    for (int m = 0; m < 16; m++){
      float x0  = xs[m][d];
      float xm1 = (d >= 1)   ? xs[m][d-1] : 0.f;
      float xp1 = (d <= 254) ? xs[m][d+1] : 0.f;
      float xp2 = (d <= 253) ? xs[m][d+2] : 0.f;
      int rowg = rt*16 + m;
      int fa = afrag_(rowg, d);
      #pragma unroll
      for (int h = 0; h < NH_; h++){
        float a2 = cb[h];
        a2 = fmaf(xm1, ck[0*NH_+h], a2);
        a2 = fmaf(x0,  ck[1*NH_+h], a2);
        a2 = fmaf(xp1, ck[2*NH_+h], a2);
        a2 = fmaf(xp2, ck[3*NH_+h], a2);
        qkb[h*(TB_*D_) + fa] = tobf_(silu_(a2));
      }
    }
    // gate dots: 64 dots (4h x 16m), 4 lanes each over 64 k
    int dot = tid >> 2, l4 = tid & 3;
    int h = dot >> 4, m = dot & 15;
    float ai = 0.f, af = 0.f;
    const float* wi = Wi + h*D_;
    const float* wf = Wf + h*D_;
    #pragma unroll 8
    for (int jj = 0; jj < 64; jj++){
      int k = l4*64 + jj;
      float xv = xs[m][k];
      ai = fmaf(xv, wi[k], ai);
      af = fmaf(xv, wf[k], af);
    }
    ai += __shfl_down(ai, 1); af += __shfl_down(af, 1);
    ai += __shfl_down(ai, 2); af += __shfl_down(af, 2);
    if (l4 == 0){
      int rowg = rt*16 + m;
      int t = rowg >> 3, b = rowg & 7;
      itb[(h*B_ + b)*T_ + t] = ai + bi[h];
      ftb[(h*B_ + b)*T_ + t] = af + bfv[h];
    }
  }
}

// ---------------- K3: per-head 5-matmul MFMA GEMM; frag-layout epilogues for attn ----------------
// grid = 5 mats x 4 heads x 16 row-tiles; block 256 = 4 waves (64 n-cols each)
__global__ __launch_bounds__(256) void k_gemm5(
    const unsigned short* __restrict__ qkb, const unsigned short* __restrict__ xinb,
    const unsigned short* __restrict__ Wqt, const unsigned short* __restrict__ Wkt,
    const unsigned short* __restrict__ Wst, const unsigned short* __restrict__ Wvt,
    const unsigned short* __restrict__ Wot,
    const float* __restrict__ bq, const float* __restrict__ bk, const float* __restrict__ bsk,
    const float* __restrict__ bv, const float* __restrict__ bo,
    unsigned short* __restrict__ qob, unsigned short* __restrict__ kob,
    unsigned short* __restrict__ vot,
    float* __restrict__ hb, float* __restrict__ og){
  int bid = blockIdx.x;
  int rt  = bid & 15;
  int h   = (bid >> 4) & 3;
  int mat = bid >> 6;                    // 0=q 1=k 2=skip 3=v 4=og
  int tid = threadIdx.x;
  int w = tid >> 6, l = tid & 63;
  int lm = l & 15, lq = l >> 4;
  int r0 = rt * 32;
  const unsigned short* A = (mat < 3) ? (qkb + h*(TB_*D_)) : xinb;
  const unsigned short* Bt;
  const float* bias;
  switch (mat){
    case 0: Bt = Wqt; bias = bq;  break;
    case 1: Bt = Wkt; bias = bk;  break;
    case 2: Bt = Wst; bias = bsk; break;
    case 3: Bt = Wvt; bias = bv;  break;
    default: Bt = Wot; bias = bo; break;
  }
  Bt += h*(D_*D_);
  f32x4 acc[2][4];
  #pragma unroll
  for (int mt = 0; mt < 2; mt++)
    #pragma unroll
    for (int nt = 0; nt < 4; nt++) acc[mt][nt] = (f32x4){0.f,0.f,0.f,0.f};
  const unsigned short* Ap = A + l*8;
  const unsigned short* Bp = Bt + l*8;
  #pragma unroll
  for (int kc = 0; kc < 8; kc++){
    bf16x8 a0 = *(const bf16x8*)(Ap + ((rt*16      + kc) << 9));
    bf16x8 a1 = *(const bf16x8*)(Ap + ((rt*16 + 8  + kc) << 9));
    bf16x8 b0 = *(const bf16x8*)(Bp + (((w*4+0)*8 + kc) << 9));
    bf16x8 b1 = *(const bf16x8*)(Bp + (((w*4+1)*8 + kc) << 9));
    bf16x8 b2 = *(const bf16x8*)(Bp + (((w*4+2)*8 + kc) << 9));
    bf16x8 b3 = *(const bf16x8*)(Bp + (((w*4+3)*8 + kc) << 9));
    acc[0][0] = __builtin_amdgcn_mfma_f32_16x16x32_bf16(a0, b0, acc[0][0], 0, 0, 0);
    acc[0][1] = __builtin_amdgcn_mfma_f32_16x16x32_bf16(a0, b1, acc[0][1], 0, 0, 0);
    acc[0][2] = __builtin_amdgcn_mfma_f32_16x16x32_bf16(a0, b2, acc[0][2], 0, 0, 0);
    acc[0][3] = __builtin_amdgcn_mfma_f32_16x16x32_bf16(a0, b3, acc[0][3], 0, 0, 0);
    acc[1][0] = __builtin_amdgcn_mfma_f32_16x16x32_bf16(a1, b0, acc[1][0], 0, 0, 0);
    acc[1][1] = __builtin_amdgcn_mfma_f32_16x16x32_bf16(a1, b1, acc[1][1], 0, 0, 0);
    acc[1][2] = __builtin_amdgcn_mfma_f32_16x16x32_bf16(a1, b2, acc[1][2], 0, 0, 0);
    acc[1][3] = __builtin_amdgcn_mfma_f32_16x16x32_bf16(a1, b3, acc[1][3], 0, 0, 0);
  }
  float bval[4];
  #pragma unroll
  for (int nt = 0; nt < 4; nt++) bval[nt] = bias[h*D_ + w*64 + nt*16 + lm];
  #pragma unroll
  for (int mt = 0; mt < 2; mt++){
    #pragma unroll
    for (int r = 0; r < 4; r++){
      int row = r0 + mt*16 + lq*4 + r;
      int t = row >> 3, b = row & 7;
      #pragma unroll
      for (int nt = 0; nt < 4; nt++){
        int e = w*64 + nt*16 + lm;
        float vv = acc[mt][nt][r] + bval[nt];
        if (mat <= 1){
          // q/k -> per-(h,b) frag (A-layout over m=t, k=e); k scaled by 1/sqrt(D)
          if (mat == 1) vv *= 0.0625f;
          unsigned short* ob = (mat == 0) ? qob : kob;
          int mt2 = t >> 4, kb2 = e >> 5;
          int lane2 = ((e >> 3)&3)*16 + (t & 15);
          ob[(h*B_ + b)*16384 + ((mt2*8 + kb2)*64 + lane2)*8 + (e & 7)] = tobf_(vv);
        } else if (mat == 3){
          // v -> per-(h,b) B-frag of V^T (n=e, k=t)
          int nt3 = e >> 4, kb3 = t >> 5;
          int lane3 = ((t >> 3)&3)*16 + lm;
          vot[(h*B_ + b)*16384 + ((nt3*2 + kb3)*64 + lane3)*8 + (t & 7)] = tobf_(vv);
        } else {
          int obase = (((t*NH_ + h)*B_ + b) << 8) + e;
          if (mat == 4) og[obase] = sigm_(vv);
          else          hb[obase] = vv;        // skip term
        }
      }
    }
  }
}

// ---------------- K4: MFMA attention with fused gate scan ----------------
// grid 128: hbx = bid>>2 (h*8+b), tq = bid&3 (16 t-rows); 4 waves: wave w = s-tile (S) / e-range (PV)
__global__ __launch_bounds__(256) void k_attn2(
    const unsigned short* __restrict__ qob, const unsigned short* __restrict__ kob,
    const unsigned short* __restrict__ vot, const float* __restrict__ og,
    const float* __restrict__ itb, const float* __restrict__ ftb,
    float* __restrict__ hb){
  __shared__ unsigned short Pf[1024];     // P bf16 A-frag (16 x 64), 2 KB
  __shared__ float partial[4][16];
  __shared__ float scal[16];
  int bid = blockIdx.x;
  int hbx = bid >> 2, tq = bid & 3;
  int h = hbx >> 3, b = hbx & 7;
  int tid = threadIdx.x;
  int w = tid >> 6, l = tid & 63, lm = l & 15, lq = l >> 4;
  // per-wave closed-form gate scan (all waves redundantly; lane = timestep)
  float F  = ftb[hbx*T_ + l];
  float it = itb[hbx*T_ + l];
  #pragma unroll
  for (int off = 1; off < 64; off <<= 1){
    float v2 = __shfl_up(F, off);
    if (l >= off) F += v2;
  }
  float ct = it - F;                       // colterm(l)
  float G = ct;
  #pragma unroll
  for (int off = 1; off < 64; off <<= 1){
    float v2 = __shfl_up(G, off);
    if (l >= off) G = fmaxf(G, v2);
  }
  float rb = -fmaxf(0.f, G);               // rowbase(l)
  // S = Q @ K^T : m-tile = tq, n(s)-tile = w
  const unsigned short* Aq = qob + hbx*16384 + l*8;
  const unsigned short* Bk = kob + hbx*16384 + l*8;
  f32x4 accs = (f32x4){0.f,0.f,0.f,0.f};
  #pragma unroll
  for (int kc = 0; kc < 8; kc++){
    bf16x8 a  = *(const bf16x8*)(Aq + ((tq*8 + kc) << 9));
    bf16x8 bb = *(const bf16x8*)(Bk + ((w*8  + kc) << 9));
    accs = __builtin_amdgcn_mfma_f32_16x16x32_bf16(a, bb, accs, 0, 0, 0);
  }
  // decay-mask-exp weights in C-layout regs; rowsum via shfl butterfly
  int s = w*16 + lm;
  float ct_s = __shfl(ct, s);
  float p[4], ps[4];
  #pragma unroll
  for (int r = 0; r < 4; r++){
    int t = tq*16 + lq*4 + r;
    float rb_t = __shfl(rb, t);
    float pv = (s <= t) ? __expf(ct_s + rb_t) * accs[r] : 0.f;
    p[r] = pv; ps[r] = pv;
  }
  #pragma unroll
  for (int off = 1; off < 16; off <<= 1){
    #pragma unroll
    for (int r = 0; r < 4; r++) ps[r] += __shfl_xor(ps[r], off);
  }
  if (lm == 0){
    #pragma unroll
    for (int r = 0; r < 4; r++) partial[w][lq*4 + r] = ps[r];
  }
  // P -> LDS bf16 A-frag (m = t-local, k = s)
  {
    int kbP = w >> 1;
    int laneP = ((w*2 + (lm >> 3)) & 3)*16;
    int jP = lm & 7;
    #pragma unroll
    for (int r = 0; r < 4; r++){
      int m = lq*4 + r;
      Pf[(kbP*64 + laneP + m)*8 + jP] = tobf_(p[r]);
    }
  }
  __syncthreads();
  if (tid < 16){
    float sum = partial[0][tid] + partial[1][tid] + partial[2][tid] + partial[3][tid];
    scal[tid] = 1.0f / fmaxf(fabsf(sum), 1.0f);   // 1/max(|n.q|,1)
  }
  // O = P @ V : e-tiles w*4..w*4+3
  bf16x8 pa0 = *(const bf16x8*)(Pf + l*8);
  bf16x8 pa1 = *(const bf16x8*)(Pf + 512 + l*8);
  const unsigned short* Bv = vot + hbx*16384 + l*8;
  f32x4 acco[4];
  #pragma unroll
  for (int nt = 0; nt < 4; nt++) acco[nt] = (f32x4){0.f,0.f,0.f,0.f};
  #pragma unroll
  for (int nt = 0; nt < 4; nt++){
    int nt3 = w*4 + nt;
    bf16x8 b0 = *(const bf16x8*)(Bv + (((nt3*2 + 0)) << 9));
    bf16x8 b1 = *(const bf16x8*)(Bv + (((nt3*2 + 1)) << 9));
    acco[nt] = __builtin_amdgcn_mfma_f32_16x16x32_bf16(pa0, b0, acco[nt], 0, 0, 0);
    acco[nt] = __builtin_amdgcn_mfma_f32_16x16x32_bf16(pa1, b1, acco[nt], 0, 0, 0);
  }
  __syncthreads();
  #pragma unroll
  for (int nt = 0; nt < 4; nt++){
    #pragma unroll
    for (int r = 0; r < 4; r++){
      int tl = lq*4 + r;
      int t = tq*16 + tl;
      int e = (w*4 + nt)*16 + lm;
      int idx = (((t*NH_ + h)*B_ + b) << 8) + e;
      hb[idx] += og[idx] * acco[nt][r] * scal[tl];
    }
  }
}

// ---------------- K5: fused bn2 + poll + down ----------------
// grid 128: t = bid>>1, bhalf = bid&1 (4 batch rows)
__global__ __launch_bounds__(256) void k_tail(
    const float* __restrict__ hbuf, const float* __restrict__ bn2s, const float* __restrict__ bn2b,
    const float* __restrict__ Wp, const float* __restrict__ bp, const float* __restrict__ trig,
    const float* __restrict__ Wd, const float* __restrict__ bd, const float* __restrict__ x,
    float* __restrict__ y){
  __shared__ __align__(16) float hs[32*D_];   // 32 KB: hbuf[t] then normalized in place
  __shared__ float zs[4][D_];                 // 4 KB
  int bid = blockIdx.x;
  int t = bid >> 1, bh = bid & 1;
  int tid = threadIdx.x;
  const float* hp = hbuf + t*(NH_*B_*D_);
  #pragma unroll
  for (int i2 = 0; i2 < 8; i2++){
    int i4 = tid + i2*256;
    *(float4*)&hs[i4*4] = *(const float4*)&hp[i4*4];
  }
  __syncthreads();
  {
    int d = tid;
    float v[32]; float mu = 0.f;
    #pragma unroll
    for (int i = 0; i < 32; i++){ v[i] = hs[i*D_ + d]; mu += v[i]; }
    mu *= (1.0f/32.0f);
    float var = 0.f;
    #pragma unroll
    for (int i = 0; i < 32; i++){ float dd = v[i]-mu; var += dd*dd; }
    var *= (1.0f/32.0f);
    float sc = (1.0f/sqrtf(var + EPS_)) * bn2s[d];
    float bs = bn2b[d];
    #pragma unroll
    for (int i = 0; i < 32; i++) hs[i*D_ + d] = (v[i]-mu)*sc + bs;
  }
  __syncthreads();
  {
    int e = tid;
    float acc4[4] = {0.f,0.f,0.f,0.f};
    #pragma unroll
    for (int h = 0; h < 4; h++){
      const float* wpp = Wp + h*256*D_ + e;
      int ib = (h*B_ + bh*4)*D_;
      for (int d4 = 0; d4 < 256; d4 += 4){
        float w0 = wpp[(d4+0)*D_], w1 = wpp[(d4+1)*D_];
        float w2 = wpp[(d4+2)*D_], w3 = wpp[(d4+3)*D_];
        #pragma unroll
        for (int bl = 0; bl < 4; bl++){
          float4 h4 = *(const float4*)&hs[ib + bl*D_ + d4];
          acc4[bl] = fmaf(h4.x, w0, fmaf(h4.y, w1, fmaf(h4.z, w2, fmaf(h4.w, w3, acc4[bl]))));
        }
      }
    }
    float bpe = bp[e];
    #pragma unroll
    for (int bl = 0; bl < 4; bl++){
      int row = t*B_ + bh*4 + bl;
      zs[bl][e] = (acc4[bl] + bpe) * trig[row*D_ + e];
    }
  }
  __syncthreads();
  {
    int hh = tid & 127, rp = tid >> 7;
    float a0 = 0.f, a1 = 0.f;
    const float* wdp = Wd + hh;
    #pragma unroll 4
    for (int e = 0; e < D_; e++){
      float wd = wdp[e*H_];
      a0 = fmaf(zs[rp][e],   wd, a0);
      a1 = fmaf(zs[rp+2][e], wd, a1);
    }
    int row0 = t*B_ + bh*4 + rp;
    int row1 = row0 + 2;
    float bde = bd[hh];
    y[row0*H_ + hh] = a0 + bde + x[row0*H_ + hh];
    y[row1*H_ + hh] = a1 + bde + x[row1*H_ + hh];
  }
}

extern "C" void kernel_launch(void* const* d_in, const int* in_sizes, int n_in,
                              void* d_out, int out_size, void* d_ws, size_t ws_size,
                              hipStream_t stream){
  const float* x     = (const float*)d_in[0];
  const float* Wq    = (const float*)d_in[1];
  const float* bq    = (const float*)d_in[2];
  const float* Wk    = (const float*)d_in[3];
  const float* bk    = (const float*)d_in[4];
  const float* Wv    = (const float*)d_in[5];
  const float* bv    = (const float*)d_in[6];
  const float* ck    = (const float*)d_in[7];
  const float* cb    = (const float*)d_in[8];
  const float* Wi    = (const float*)d_in[9];
  const float* bi    = (const float*)d_in[10];
  const float* Wf    = (const float*)d_in[11];
  const float* bf    = (const float*)d_in[12];
  const float* Wo    = (const float*)d_in[13];
  const float* bo    = (const float*)d_in[14];
  const float* Wsk   = (const float*)d_in[15];
  const float* bsk   = (const float*)d_in[16];
  const float* bn1s  = (const float*)d_in[17];
  const float* bn1b  = (const float*)d_in[18];
  const float* bn2s  = (const float*)d_in[19];
  const float* bn2b  = (const float*)d_in[20];
  const float* Wup1  = (const float*)d_in[21];
  const float* bup1  = (const float*)d_in[22];
  const float* Wup2  = (const float*)d_in[23];
  const float* bup2  = (const float*)d_in[24];
  const float* Wp    = (const float*)d_in[25];
  const float* bp    = (const float*)d_in[26];
  const float* Wd    = (const float*)d_in[27];
  const float* bd    = (const float*)d_in[28];
  float* y = (float*)d_out;

  float* w = (float*)d_ws;
  float* trig = w;  w += T_*B_*D_;
  float* hbuf = w;  w += T_*NH_*B_*D_;
  float* og   = w;  w += T_*NH_*B_*D_;
  float* itb  = w;  w += NH_*B_*T_;
  float* ftb  = w;  w += NH_*B_*T_;
  unsigned short* xinb = (unsigned short*)w;  w += (T_*B_*D_)/2;
  unsigned short* qkb  = (unsigned short*)w;  w += (NH_*TB_*D_)/2;
  unsigned short* Wqt  = (unsigned short*)w;  w += (NH_*D_*D_)/2;
  unsigned short* Wkt  = (unsigned short*)w;  w += (NH_*D_*D_)/2;
  unsigned short* Wst  = (unsigned short*)w;  w += (NH_*D_*D_)/2;
  unsigned short* Wvt  = (unsigned short*)w;  w += (NH_*D_*D_)/2;
  unsigned short* Wot  = (unsigned short*)w;  w += (NH_*D_*D_)/2;
  unsigned short* Wu1t = (unsigned short*)w;  w += (H_*D_)/2;
  unsigned short* Wu2t = (unsigned short*)w;  w += (H_*D_)/2;
  unsigned short* ub   = (unsigned short*)w;  w += (TB_*H_)/2;
  unsigned short* qob  = (unsigned short*)w;  w += (NH_*B_*T_*D_)/2;
  unsigned short* kob  = (unsigned short*)w;  w += (NH_*B_*T_*D_)/2;
  unsigned short* vot  = (unsigned short*)w;  w += (NH_*B_*T_*D_)/2;

  k_prep <<<704, 256, 0, stream>>>(Wq, Wk, Wsk, Wv, Wo, Wup1, Wup2, x, bn1s, bn1b,
                                   Wqt, Wkt, Wst, Wvt, Wot, Wu1t, Wu2t, ub);
  k_upcg <<<64, 256, 0, stream>>>(ub, Wu1t, Wu2t, bup1, bup2, ck, cb, Wi, bi, Wf, bf,
                                  xinb, qkb, trig, itb, ftb);
  k_gemm5<<<320, 256, 0, stream>>>(qkb, xinb, Wqt, Wkt, Wst, Wvt, Wot,
                                   bq, bk, bsk, bv, bo, qob, kob, vot, hbuf, og);
  k_attn2<<<NH_*B_*4, 256, 0, stream>>>(qob, kob, vot, og, itb, ftb, hbuf);
  k_tail <<<T_*2, 256, 0, stream>>>(hbuf, bn2s, bn2b, Wp, bp, trig, Wd, bd, x, y);
}

// Round 6
// 157.487 us; speedup vs baseline: 2.0762x; 1.1918x over previous
//
#include <hip/hip_runtime.h>
#include <hip/hip_bf16.h>

#define T_ 64
#define B_ 8
#define H_ 128
#define NH_ 4
#define D_ 256
#define TB_ 512          // T_*B_
#define EPS_ 1e-5f

typedef short bf16x8 __attribute__((ext_vector_type(8)));
typedef float f32x4 __attribute__((ext_vector_type(4)));

__device__ __forceinline__ float silu_(float x){ return x / (1.0f + __expf(-x)); }
__device__ __forceinline__ float sigm_(float x){ return 1.0f / (1.0f + __expf(-x)); }
__device__ __forceinline__ unsigned short tobf_(float f){
  unsigned u = __float_as_uint(f);
  u += 0x7FFF + ((u >> 16) & 1);          // round-to-nearest-even
  return (unsigned short)(u >> 16);
}
// A-fragment-linear address, element (m,k) of [M x 256] bf16 matrix (K=256)
__device__ __forceinline__ int afrag_(int m, int k){
  return (((m >> 4)*8 + (k >> 5))*64 + ((k >> 3)&3)*16 + (m & 15))*8 + (k & 7);
}
// generalized for K=1024 (32 kb per m-tile)
__device__ __forceinline__ int afrag1024_(int m, int k){
  return (((m >> 4)*32 + (k >> 5))*64 + ((k >> 3)&3)*16 + (m & 15))*8 + (k & 7);
}

// ---------------- K1: all weight conversions + bn1 + u (A-frag bf16) ----------------
// 0..639: Wq/Wk/Ws/Wv/Wo B-frag | 640..671: Wup1/2 B-frag K=128 | 672..703: bn1->u A-frag
// 704..831: Wpoll B-frag K=1024 | 832..847: Wdown B-frag K=256
__global__ __launch_bounds__(256) void k_prep(
    const float* __restrict__ Wq, const float* __restrict__ Wk, const float* __restrict__ Ws,
    const float* __restrict__ Wv, const float* __restrict__ Wo,
    const float* __restrict__ Wup1, const float* __restrict__ Wup2,
    const float* __restrict__ Wp, const float* __restrict__ Wd,
    const float* __restrict__ x, const float* __restrict__ bn1s, const float* __restrict__ bn1b,
    unsigned short* __restrict__ Wqt, unsigned short* __restrict__ Wkt,
    unsigned short* __restrict__ Wst, unsigned short* __restrict__ Wvt,
    unsigned short* __restrict__ Wot,
    unsigned short* __restrict__ Wu1t, unsigned short* __restrict__ Wu2t,
    unsigned short* __restrict__ Wpt, unsigned short* __restrict__ Wdt,
    unsigned short* __restrict__ ub){
  int bid = blockIdx.x;
  int tid = threadIdx.x;
  if (bid < 640){
    int sub = bid & 31;
    int h   = (bid >> 5) & 3;
    int mat = bid >> 7;
    const float* Win; unsigned short* Wout;
    switch (mat){
      case 0: Win = Wq; Wout = Wqt; break;
      case 1: Win = Wk; Wout = Wkt; break;
      case 2: Win = Ws; Wout = Wst; break;
      case 3: Win = Wv; Wout = Wvt; break;
      default: Win = Wo; Wout = Wot; break;
    }
    Win  += h * (D_*D_);
    Wout += h * (D_*D_);
    int gid = sub*256 + tid;
    int combo = gid >> 6;                // nt*8 + kb
    int l = gid & 63;
    int lm = l & 15, lq = l >> 4;
    int nt = combo >> 3, kb = combo & 7;
    int n = nt*16 + lm;
    int k0 = kb*32 + lq*8;
    bf16x8 v;
    #pragma unroll
    for (int j = 0; j < 8; j++) v[j] = (short)tobf_(Win[(k0+j)*D_ + n]);
    *(bf16x8*)(Wout + (combo*64 + l)*8) = v;
  } else if (bid < 672){
    int idx = bid - 640;
    const float* Win = (idx < 16) ? Wup1 : Wup2;
    unsigned short* Wout = (idx < 16) ? Wu1t : Wu2t;
    int sub = idx & 15;
    int gid = sub*256 + tid;             // [0,4096)
    int combo = gid >> 6;                // nt*4 + kb  (K=128)
    int l = gid & 63;
    int lm = l & 15, lq = l >> 4;
    int nt = combo >> 2, kb = combo & 3;
    int n = nt*16 + lm;
    int k0 = kb*32 + lq*8;
    bf16x8 v;
    #pragma unroll
    for (int j = 0; j < 8; j++) v[j] = (short)tobf_(Win[(k0+j)*D_ + n]);
    *(bf16x8*)(Wout + (combo*64 + l)*8) = v;
  } else if (bid < 704){
    int i = bid - 672;                   // m-tile pair
    int tt = tid >> 7, hf = tid & 127;
    int t = i*2 + tt;
    const float* xp = x + t*(B_*H_) + hf;
    float v0[8]; float mu = 0.f;
    #pragma unroll
    for (int b = 0; b < 8; b++){ v0[b] = xp[b*H_]; mu += v0[b]; }
    mu *= 0.125f;
    float var = 0.f;
    #pragma unroll
    for (int b = 0; b < 8; b++){ float dd = v0[b]-mu; var += dd*dd; }
    var *= 0.125f;
    float sc = (1.0f/sqrtf(var + EPS_)) * bn1s[hf];
    float bs = bn1b[hf];
    int kb = hf >> 5, j = hf & 7;
    int lanebase = ((hf >> 3)&3)*16 + tt*8;
    unsigned short* up = ub + ((i*4 + kb)*64)*8 + j;
    #pragma unroll
    for (int b = 0; b < 8; b++)
      up[(lanebase + b)*8] = tobf_((v0[b]-mu)*sc + bs);
  } else if (bid < 832){
    // Wpoll [1024 x 256] -> B-frag K=1024
    int gid = (bid - 704)*256 + tid;     // [0, 32768)
    int combo = gid >> 6;                // nt*32 + kb
    int l = gid & 63;
    int lm = l & 15, lq = l >> 4;
    int nt = combo >> 5, kb = combo & 31;
    int n = nt*16 + lm;
    int k0 = kb*32 + lq*8;
    bf16x8 v;
    #pragma unroll
    for (int j = 0; j < 8; j++) v[j] = (short)tobf_(Wp[(k0+j)*D_ + n]);
    *(bf16x8*)(Wpt + (combo*64 + l)*8) = v;
  } else {
    // Wdown [256 x 128] -> B-frag K=256
    int gid = (bid - 832)*256 + tid;     // [0, 4096)
    int combo = gid >> 6;                // nt*8 + kb
    int l = gid & 63;
    int lm = l & 15, lq = l >> 4;
    int nt = combo >> 3, kb = combo & 7;
    int n = nt*16 + lm;
    int k0 = kb*32 + lq*8;
    bf16x8 v;
    #pragma unroll
    for (int j = 0; j < 8; j++) v[j] = (short)tobf_(Wd[(k0+j)*H_ + n]);
    *(bf16x8*)(Wdt + (combo*64 + l)*8) = v;
  }
}

// ---------------- K2: up-proj MFMA GEMM + fused conv/gates (mat0) / trig (mat1) ----------------
__global__ __launch_bounds__(256) void k_upcg(
    const unsigned short* __restrict__ ub,
    const unsigned short* __restrict__ Wu1t, const unsigned short* __restrict__ Wu2t,
    const float* __restrict__ bup1, const float* __restrict__ bup2,
    const float* __restrict__ ck, const float* __restrict__ cb,
    const float* __restrict__ Wi, const float* __restrict__ bi,
    const float* __restrict__ Wf, const float* __restrict__ bfv,
    unsigned short* __restrict__ xinb, unsigned short* __restrict__ qkb,
    float* __restrict__ trig, float* __restrict__ itb, float* __restrict__ ftb){
  __shared__ float xs[16][257];
  int bid = blockIdx.x;
  int mat = bid >> 5, rt = bid & 31;
  int tid = threadIdx.x;
  int w = tid >> 6, l = tid & 63, lm = l & 15, lq = l >> 4;
  const unsigned short* Bt = (mat == 0) ? Wu1t : Wu2t;
  f32x4 acc[4];
  #pragma unroll
  for (int nt = 0; nt < 4; nt++) acc[nt] = (f32x4){0.f,0.f,0.f,0.f};
  const unsigned short* Ap = ub + l*8;
  const unsigned short* Bp = Bt + l*8;
  #pragma unroll
  for (int kb = 0; kb < 4; kb++){
    bf16x8 a = *(const bf16x8*)(Ap + ((rt*4 + kb) << 9));
    #pragma unroll
    for (int nt = 0; nt < 4; nt++){
      bf16x8 bfr = *(const bf16x8*)(Bp + (((w*4+nt)*4 + kb) << 9));
      acc[nt] = __builtin_amdgcn_mfma_f32_16x16x32_bf16(a, bfr, acc[nt], 0, 0, 0);
    }
  }
  const float* bias = (mat == 0) ? bup1 : bup2;
  #pragma unroll
  for (int nt = 0; nt < 4; nt++){
    #pragma unroll
    for (int r = 0; r < 4; r++){
      int m = lq*4 + r;
      int row = rt*16 + m;
      int e = w*64 + nt*16 + lm;
      float vv = acc[nt][r] + bias[e];
      if (mat == 1){
        trig[row*D_ + e] = silu_(vv);
      } else {
        xinb[afrag_(row, e)] = tobf_(vv);
        xs[m][e] = vv;
      }
    }
  }
  if (mat == 0){
    __syncthreads();
    int d = tid;
    #pragma unroll 4
    for (int m = 0; m < 16; m++){
      float x0  = xs[m][d];
      float xm1 = (d >= 1)   ? xs[m][d-1] : 0.f;
      float xp1 = (d <= 254) ? xs[m][d+1] : 0.f;
      float xp2 = (d <= 253) ? xs[m][d+2] : 0.f;
      int rowg = rt*16 + m;
      int fa = afrag_(rowg, d);
      #pragma unroll
      for (int h = 0; h < NH_; h++){
        float a2 = cb[h];
        a2 = fmaf(xm1, ck[0*NH_+h], a2);
        a2 = fmaf(x0,  ck[1*NH_+h], a2);
        a2 = fmaf(xp1, ck[2*NH_+h], a2);
        a2 = fmaf(xp2, ck[3*NH_+h], a2);
        qkb[h*(TB_*D_) + fa] = tobf_(silu_(a2));
      }
    }
    int dot = tid >> 2, l4 = tid & 3;
    int h = dot >> 4, m = dot & 15;
    float ai = 0.f, af = 0.f;
    const float* wi = Wi + h*D_;
    const float* wf = Wf + h*D_;
    #pragma unroll 8
    for (int jj = 0; jj < 64; jj++){
      int k = l4*64 + jj;
      float xv = xs[m][k];
      ai = fmaf(xv, wi[k], ai);
      af = fmaf(xv, wf[k], af);
    }
    ai += __shfl_down(ai, 1); af += __shfl_down(af, 1);
    ai += __shfl_down(ai, 2); af += __shfl_down(af, 2);
    if (l4 == 0){
      int rowg = rt*16 + m;
      int t = rowg >> 3, b = rowg & 7;
      itb[(h*B_ + b)*T_ + t] = ai + bi[h];
      ftb[(h*B_ + b)*T_ + t] = af + bfv[h];
    }
  }
}

// ---------------- K3: per-head 5-matmul MFMA GEMM; frag-layout epilogues for attn ----------------
__global__ __launch_bounds__(256) void k_gemm5(
    const unsigned short* __restrict__ qkb, const unsigned short* __restrict__ xinb,
    const unsigned short* __restrict__ Wqt, const unsigned short* __restrict__ Wkt,
    const unsigned short* __restrict__ Wst, const unsigned short* __restrict__ Wvt,
    const unsigned short* __restrict__ Wot,
    const float* __restrict__ bq, const float* __restrict__ bk, const float* __restrict__ bsk,
    const float* __restrict__ bv, const float* __restrict__ bo,
    unsigned short* __restrict__ qob, unsigned short* __restrict__ kob,
    unsigned short* __restrict__ vot,
    float* __restrict__ hb, float* __restrict__ og){
  int bid = blockIdx.x;
  int rt  = bid & 15;
  int h   = (bid >> 4) & 3;
  int mat = bid >> 6;                    // 0=q 1=k 2=skip 3=v 4=og
  int tid = threadIdx.x;
  int w = tid >> 6, l = tid & 63;
  int lm = l & 15, lq = l >> 4;
  int r0 = rt * 32;
  const unsigned short* A = (mat < 3) ? (qkb + h*(TB_*D_)) : xinb;
  const unsigned short* Bt;
  const float* bias;
  switch (mat){
    case 0: Bt = Wqt; bias = bq;  break;
    case 1: Bt = Wkt; bias = bk;  break;
    case 2: Bt = Wst; bias = bsk; break;
    case 3: Bt = Wvt; bias = bv;  break;
    default: Bt = Wot; bias = bo; break;
  }
  Bt += h*(D_*D_);
  f32x4 acc[2][4];
  #pragma unroll
  for (int mt = 0; mt < 2; mt++)
    #pragma unroll
    for (int nt = 0; nt < 4; nt++) acc[mt][nt] = (f32x4){0.f,0.f,0.f,0.f};
  const unsigned short* Ap = A + l*8;
  const unsigned short* Bp = Bt + l*8;
  #pragma unroll
  for (int kc = 0; kc < 8; kc++){
    bf16x8 a0 = *(const bf16x8*)(Ap + ((rt*16      + kc) << 9));
    bf16x8 a1 = *(const bf16x8*)(Ap + ((rt*16 + 8  + kc) << 9));
    bf16x8 b0 = *(const bf16x8*)(Bp + (((w*4+0)*8 + kc) << 9));
    bf16x8 b1 = *(const bf16x8*)(Bp + (((w*4+1)*8 + kc) << 9));
    bf16x8 b2 = *(const bf16x8*)(Bp + (((w*4+2)*8 + kc) << 9));
    bf16x8 b3 = *(const bf16x8*)(Bp + (((w*4+3)*8 + kc) << 9));
    acc[0][0] = __builtin_amdgcn_mfma_f32_16x16x32_bf16(a0, b0, acc[0][0], 0, 0, 0);
    acc[0][1] = __builtin_amdgcn_mfma_f32_16x16x32_bf16(a0, b1, acc[0][1], 0, 0, 0);
    acc[0][2] = __builtin_amdgcn_mfma_f32_16x16x32_bf16(a0, b2, acc[0][2], 0, 0, 0);
    acc[0][3] = __builtin_amdgcn_mfma_f32_16x16x32_bf16(a0, b3, acc[0][3], 0, 0, 0);
    acc[1][0] = __builtin_amdgcn_mfma_f32_16x16x32_bf16(a1, b0, acc[1][0], 0, 0, 0);
    acc[1][1] = __builtin_amdgcn_mfma_f32_16x16x32_bf16(a1, b1, acc[1][1], 0, 0, 0);
    acc[1][2] = __builtin_amdgcn_mfma_f32_16x16x32_bf16(a1, b2, acc[1][2], 0, 0, 0);
    acc[1][3] = __builtin_amdgcn_mfma_f32_16x16x32_bf16(a1, b3, acc[1][3], 0, 0, 0);
  }
  float bval[4];
  #pragma unroll
  for (int nt = 0; nt < 4; nt++) bval[nt] = bias[h*D_ + w*64 + nt*16 + lm];
  #pragma unroll
  for (int mt = 0; mt < 2; mt++){
    #pragma unroll
    for (int r = 0; r < 4; r++){
      int row = r0 + mt*16 + lq*4 + r;
      int t = row >> 3, b = row & 7;
      #pragma unroll
      for (int nt = 0; nt < 4; nt++){
        int e = w*64 + nt*16 + lm;
        float vv = acc[mt][nt][r] + bval[nt];
        if (mat <= 1){
          if (mat == 1) vv *= 0.0625f;
          unsigned short* ob = (mat == 0) ? qob : kob;
          int mt2 = t >> 4, kb2 = e >> 5;
          int lane2 = ((e >> 3)&3)*16 + (t & 15);
          ob[(h*B_ + b)*16384 + ((mt2*8 + kb2)*64 + lane2)*8 + (e & 7)] = tobf_(vv);
        } else if (mat == 3){
          int nt3 = e >> 4, kb3 = t >> 5;
          int lane3 = ((t >> 3)&3)*16 + lm;
          vot[(h*B_ + b)*16384 + ((nt3*2 + kb3)*64 + lane3)*8 + (t & 7)] = tobf_(vv);
        } else {
          int obase = (((t*NH_ + h)*B_ + b) << 8) + e;
          if (mat == 4) og[obase] = sigm_(vv);
          else          hb[obase] = vv;        // skip term
        }
      }
    }
  }
}

// ---------------- K4: MFMA attention with fused gate scan ----------------
__global__ __launch_bounds__(256) void k_attn2(
    const unsigned short* __restrict__ qob, const unsigned short* __restrict__ kob,
    const unsigned short* __restrict__ vot, const float* __restrict__ og,
    const float* __restrict__ itb, const float* __restrict__ ftb,
    float* __restrict__ hb){
  __shared__ unsigned short Pf[1024];
  __shared__ float partial[4][16];
  __shared__ float scal[16];
  int bid = blockIdx.x;
  int hbx = bid >> 2, tq = bid & 3;
  int h = hbx >> 3, b = hbx & 7;
  int tid = threadIdx.x;
  int w = tid >> 6, l = tid & 63, lm = l & 15, lq = l >> 4;
  float F  = ftb[hbx*T_ + l];
  float it = itb[hbx*T_ + l];
  #pragma unroll
  for (int off = 1; off < 64; off <<= 1){
    float v2 = __shfl_up(F, off);
    if (l >= off) F += v2;
  }
  float ct = it - F;
  float G = ct;
  #pragma unroll
  for (int off = 1; off < 64; off <<= 1){
    float v2 = __shfl_up(G, off);
    if (l >= off) G = fmaxf(G, v2);
  }
  float rb = -fmaxf(0.f, G);
  const unsigned short* Aq = qob + hbx*16384 + l*8;
  const unsigned short* Bk = kob + hbx*16384 + l*8;
  f32x4 accs = (f32x4){0.f,0.f,0.f,0.f};
  #pragma unroll
  for (int kc = 0; kc < 8; kc++){
    bf16x8 a  = *(const bf16x8*)(Aq + ((tq*8 + kc) << 9));
    bf16x8 bb = *(const bf16x8*)(Bk + ((w*8  + kc) << 9));
    accs = __builtin_amdgcn_mfma_f32_16x16x32_bf16(a, bb, accs, 0, 0, 0);
  }
  int s = w*16 + lm;
  float ct_s = __shfl(ct, s);
  float p[4], ps[4];
  #pragma unroll
  for (int r = 0; r < 4; r++){
    int t = tq*16 + lq*4 + r;
    float rb_t = __shfl(rb, t);
    float pv = (s <= t) ? __expf(ct_s + rb_t) * accs[r] : 0.f;
    p[r] = pv; ps[r] = pv;
  }
  #pragma unroll
  for (int off = 1; off < 16; off <<= 1){
    #pragma unroll
    for (int r = 0; r < 4; r++) ps[r] += __shfl_xor(ps[r], off);
  }
  if (lm == 0){
    #pragma unroll
    for (int r = 0; r < 4; r++) partial[w][lq*4 + r] = ps[r];
  }
  {
    int kbP = w >> 1;
    int laneP = ((w*2 + (lm >> 3)) & 3)*16;
    int jP = lm & 7;
    #pragma unroll
    for (int r = 0; r < 4; r++){
      int m = lq*4 + r;
      Pf[(kbP*64 + laneP + m)*8 + jP] = tobf_(p[r]);
    }
  }
  __syncthreads();
  if (tid < 16){
    float sum = partial[0][tid] + partial[1][tid] + partial[2][tid] + partial[3][tid];
    scal[tid] = 1.0f / fmaxf(fabsf(sum), 1.0f);
  }
  bf16x8 pa0 = *(const bf16x8*)(Pf + l*8);
  bf16x8 pa1 = *(const bf16x8*)(Pf + 512 + l*8);
  const unsigned short* Bv = vot + hbx*16384 + l*8;
  f32x4 acco[4];
  #pragma unroll
  for (int nt = 0; nt < 4; nt++) acco[nt] = (f32x4){0.f,0.f,0.f,0.f};
  #pragma unroll
  for (int nt = 0; nt < 4; nt++){
    int nt3 = w*4 + nt;
    bf16x8 b0 = *(const bf16x8*)(Bv + (((nt3*2 + 0)) << 9));
    bf16x8 b1 = *(const bf16x8*)(Bv + (((nt3*2 + 1)) << 9));
    acco[nt] = __builtin_amdgcn_mfma_f32_16x16x32_bf16(pa0, b0, acco[nt], 0, 0, 0);
    acco[nt] = __builtin_amdgcn_mfma_f32_16x16x32_bf16(pa1, b1, acco[nt], 0, 0, 0);
  }
  __syncthreads();
  #pragma unroll
  for (int nt = 0; nt < 4; nt++){
    #pragma unroll
    for (int r = 0; r < 4; r++){
      int tl = lq*4 + r;
      int t = tq*16 + tl;
      int e = (w*4 + nt)*16 + lm;
      int idx = (((t*NH_ + h)*B_ + b) << 8) + e;
      hb[idx] += og[idx] * acco[nt][r] * scal[tl];
    }
  }
}

// ---------------- K5a: bn2 -> hob (bf16 A-frag, M=512, K=1024) ----------------
// grid 64 (one t per block), 256 threads = d
__global__ __launch_bounds__(256) void k_bn2f(
    const float* __restrict__ hbuf, const float* __restrict__ bn2s, const float* __restrict__ bn2b,
    unsigned short* __restrict__ hob){
  int t = blockIdx.x;
  int d = threadIdx.x;
  const float* hp = hbuf + (t*NH_*B_)*D_ + d;
  float v[32]; float mu = 0.f;
  #pragma unroll
  for (int i = 0; i < 32; i++){ v[i] = hp[i*D_]; mu += v[i]; }
  mu *= (1.0f/32.0f);
  float var = 0.f;
  #pragma unroll
  for (int i = 0; i < 32; i++){ float dd = v[i]-mu; var += dd*dd; }
  var *= (1.0f/32.0f);
  float sc = (1.0f/sqrtf(var + EPS_)) * bn2s[d];
  float bs = bn2b[d];
  #pragma unroll
  for (int i = 0; i < 32; i++){          // i = h*8 + b
    int hh = i >> 3, b = i & 7;
    int m = t*B_ + b;
    int k = hh*D_ + d;
    hob[afrag1024_(m, k)] = tobf_((v[i]-mu)*sc + bs);
  }
}

// ---------------- K5b: MFMA poll (K=1024, *trig) + down (K=256, +x) ----------------
// grid 16 (32-row tiles), block 512 = 8 waves
__global__ __launch_bounds__(512) void k_tail2(
    const unsigned short* __restrict__ hob, const unsigned short* __restrict__ Wpt,
    const float* __restrict__ bp, const float* __restrict__ trig,
    const unsigned short* __restrict__ Wdt, const float* __restrict__ bd,
    const float* __restrict__ x, float* __restrict__ y){
  __shared__ unsigned short zf[32*256];   // z bf16 A-frag (local M=32, K=256), 16 KB
  int rt = blockIdx.x;
  int tid = threadIdx.x;
  int w = tid >> 6, l = tid & 63, lm = l & 15, lq = l >> 4;
  // Phase A: poll GEMM. wave w -> cols w*32..w*32+31 (2 n-tiles); 2 m-tiles
  f32x4 acc[2][2];
  #pragma unroll
  for (int mt = 0; mt < 2; mt++)
    #pragma unroll
    for (int nt = 0; nt < 2; nt++) acc[mt][nt] = (f32x4){0.f,0.f,0.f,0.f};
  const unsigned short* Ap = hob + l*8;
  const unsigned short* Bp = Wpt + l*8;
  #pragma unroll 4
  for (int kc = 0; kc < 32; kc++){
    bf16x8 a0 = *(const bf16x8*)(Ap + (((rt*2+0)*32 + kc) << 9));
    bf16x8 a1 = *(const bf16x8*)(Ap + (((rt*2+1)*32 + kc) << 9));
    bf16x8 b0 = *(const bf16x8*)(Bp + (((w*2+0)*32 + kc) << 9));
    bf16x8 b1 = *(const bf16x8*)(Bp + (((w*2+1)*32 + kc) << 9));
    acc[0][0] = __builtin_amdgcn_mfma_f32_16x16x32_bf16(a0, b0, acc[0][0], 0, 0, 0);
    acc[0][1] = __builtin_amdgcn_mfma_f32_16x16x32_bf16(a0, b1, acc[0][1], 0, 0, 0);
    acc[1][0] = __builtin_amdgcn_mfma_f32_16x16x32_bf16(a1, b0, acc[1][0], 0, 0, 0);
    acc[1][1] = __builtin_amdgcn_mfma_f32_16x16x32_bf16(a1, b1, acc[1][1], 0, 0, 0);
  }
  #pragma unroll
  for (int mt = 0; mt < 2; mt++){
    #pragma unroll
    for (int nt = 0; nt < 2; nt++){
      int e = w*32 + nt*16 + lm;
      float bpe = bp[e];
      #pragma unroll
      for (int r = 0; r < 4; r++){
        int ml = mt*16 + lq*4 + r;
        int row = rt*32 + ml;
        float z = (acc[mt][nt][r] + bpe) * trig[row*D_ + e];
        zf[afrag_(ml, e)] = tobf_(z);
      }
    }
  }
  __syncthreads();
  // Phase B: down GEMM from LDS. wave w -> n-tile w (16 cols of 128); 2 m-tiles
  f32x4 acc2[2];
  acc2[0] = (f32x4){0.f,0.f,0.f,0.f};
  acc2[1] = (f32x4){0.f,0.f,0.f,0.f};
  const unsigned short* Bdp = Wdt + l*8;
  #pragma unroll
  for (int kc = 0; kc < 8; kc++){
    bf16x8 a0 = *(const bf16x8*)(zf + ((0*8 + kc) << 9) + l*8);
    bf16x8 a1 = *(const bf16x8*)(zf + ((1*8 + kc) << 9) + l*8);
    bf16x8 bb = *(const bf16x8*)(Bdp + ((w*8 + kc) << 9));
    acc2[0] = __builtin_amdgcn_mfma_f32_16x16x32_bf16(a0, bb, acc2[0], 0, 0, 0);
    acc2[1] = __builtin_amdgcn_mfma_f32_16x16x32_bf16(a1, bb, acc2[1], 0, 0, 0);
  }
  int hh = w*16 + lm;
  float bde = bd[hh];
  #pragma unroll
  for (int mt = 0; mt < 2; mt++){
    #pragma unroll
    for (int r = 0; r < 4; r++){
      int row = rt*32 + mt*16 + lq*4 + r;
      y[row*H_ + hh] = acc2[mt][r] + bde + x[row*H_ + hh];
    }
  }
}

extern "C" void kernel_launch(void* const* d_in, const int* in_sizes, int n_in,
                              void* d_out, int out_size, void* d_ws, size_t ws_size,
                              hipStream_t stream){
  const float* x     = (const float*)d_in[0];
  const float* Wq    = (const float*)d_in[1];
  const float* bq    = (const float*)d_in[2];
  const float* Wk    = (const float*)d_in[3];
  const float* bk    = (const float*)d_in[4];
  const float* Wv    = (const float*)d_in[5];
  const float* bv    = (const float*)d_in[6];
  const float* ck    = (const float*)d_in[7];
  const float* cb    = (const float*)d_in[8];
  const float* Wi    = (const float*)d_in[9];
  const float* bi    = (const float*)d_in[10];
  const float* Wf    = (const float*)d_in[11];
  const float* bf    = (const float*)d_in[12];
  const float* Wo    = (const float*)d_in[13];
  const float* bo    = (const float*)d_in[14];
  const float* Wsk   = (const float*)d_in[15];
  const float* bsk   = (const float*)d_in[16];
  const float* bn1s  = (const float*)d_in[17];
  const float* bn1b  = (const float*)d_in[18];
  const float* bn2s  = (const float*)d_in[19];
  const float* bn2b  = (const float*)d_in[20];
  const float* Wup1  = (const float*)d_in[21];
  const float* bup1  = (const float*)d_in[22];
  const float* Wup2  = (const float*)d_in[23];
  const float* bup2  = (const float*)d_in[24];
  const float* Wp    = (const float*)d_in[25];
  const float* bp    = (const float*)d_in[26];
  const float* Wd    = (const float*)d_in[27];
  const float* bd    = (const float*)d_in[28];
  float* y = (float*)d_out;

  float* w = (float*)d_ws;
  float* trig = w;  w += T_*B_*D_;
  float* hbuf = w;  w += T_*NH_*B_*D_;
  float* og   = w;  w += T_*NH_*B_*D_;
  float* itb  = w;  w += NH_*B_*T_;
  float* ftb  = w;  w += NH_*B_*T_;
  unsigned short* xinb = (unsigned short*)w;  w += (T_*B_*D_)/2;
  unsigned short* qkb  = (unsigned short*)w;  w += (NH_*TB_*D_)/2;
  unsigned short* Wqt  = (unsigned short*)w;  w += (NH_*D_*D_)/2;
  unsigned short* Wkt  = (unsigned short*)w;  w += (NH_*D_*D_)/2;
  unsigned short* Wst  = (unsigned short*)w;  w += (NH_*D_*D_)/2;
  unsigned short* Wvt  = (unsigned short*)w;  w += (NH_*D_*D_)/2;
  unsigned short* Wot  = (unsigned short*)w;  w += (NH_*D_*D_)/2;
  unsigned short* Wu1t = (unsigned short*)w;  w += (H_*D_)/2;
  unsigned short* Wu2t = (unsigned short*)w;  w += (H_*D_)/2;
  unsigned short* ub   = (unsigned short*)w;  w += (TB_*H_)/2;
  unsigned short* qob  = (unsigned short*)w;  w += (NH_*B_*T_*D_)/2;
  unsigned short* kob  = (unsigned short*)w;  w += (NH_*B_*T_*D_)/2;
  unsigned short* vot  = (unsigned short*)w;  w += (NH_*B_*T_*D_)/2;
  unsigned short* hob  = (unsigned short*)w;  w += (TB_*NH_*D_)/2;
  unsigned short* Wpt  = (unsigned short*)w;  w += (NH_*D_*D_)/2;
  unsigned short* Wdt  = (unsigned short*)w;  w += (D_*H_)/2;

  k_prep <<<848, 256, 0, stream>>>(Wq, Wk, Wsk, Wv, Wo, Wup1, Wup2, Wp, Wd, x, bn1s, bn1b,
                                   Wqt, Wkt, Wst, Wvt, Wot, Wu1t, Wu2t, Wpt, Wdt, ub);
  k_upcg <<<64, 256, 0, stream>>>(ub, Wu1t, Wu2t, bup1, bup2, ck, cb, Wi, bi, Wf, bf,
                                  xinb, qkb, trig, itb, ftb);
  k_gemm5<<<320, 256, 0, stream>>>(qkb, xinb, Wqt, Wkt, Wst, Wvt, Wot,
                                   bq, bk, bsk, bv, bo, qob, kob, vot, hbuf, og);
  k_attn2<<<NH_*B_*4, 256, 0, stream>>>(qob, kob, vot, og, itb, ftb, hbuf);
  k_bn2f <<<T_, 256, 0, stream>>>(hbuf, bn2s, bn2b, hob);
  k_tail2<<<16, 512, 0, stream>>>(hob, Wpt, bp, trig, Wdt, bd, x, y);
}